// Round 1
// 1075.568 us; speedup vs baseline: 1.8688x; 1.8688x over previous
//
#include <hip/hip_runtime.h>
#include <math.h>

typedef unsigned short u16;
typedef short bf16x8 __attribute__((ext_vector_type(8)));
typedef float f32x4 __attribute__((ext_vector_type(4)));
typedef u16 u16x2 __attribute__((ext_vector_type(2)));
typedef u16 u16x4 __attribute__((ext_vector_type(4)));
typedef u16 u16x8 __attribute__((ext_vector_type(8)));

#define MFMA16(a, b, c) __builtin_amdgcn_mfma_f32_16x16x32_bf16(a, b, c, 0, 0, 0)

// direct global->LDS async copy, 16B per lane; dest = wave-uniform base + lane*16
#define GLL16(g, l)                                                  \
    __builtin_amdgcn_global_load_lds(                                \
        (__attribute__((address_space(1))) void*)(g),                \
        (__attribute__((address_space(3))) void*)(l), 16, 0, 0)

__device__ __forceinline__ float bf2f(u16 u) {
    union { unsigned int i; float f; } v;
    v.i = ((unsigned int)u) << 16;
    return v.f;
}
__device__ __forceinline__ u16 f2bf(float f) {
    union { float f; unsigned int i; } v;
    v.f = f;
    unsigned int r = (v.i + 0x7FFFu + ((v.i >> 16) & 1u)) >> 16;
    return (u16)r;
}
__device__ __forceinline__ u16x4 cvt4(f32x4 v) {
    u16x4 r;
#pragma unroll
    for (int j = 0; j < 4; ++j) r[j] = f2bf(v[j]);
    return r;
}

// ---------------------------------------------------------------------------
// Elementwise f32 -> bf16 (RNE), 8 elems/thread/iter, grid-stride.
// n8 = element count / 8 (all our sizes are multiples of 8).
// ---------------------------------------------------------------------------
__global__ __launch_bounds__(256)
void cvt_bf16(const float* __restrict__ in, u16* __restrict__ out, int n8) {
    int i = blockIdx.x * 256 + threadIdx.x;
    const int stride = gridDim.x * 256;
    for (; i < n8; i += stride) {
        f32x4 a = ((const f32x4*)in)[2 * i];
        f32x4 b = ((const f32x4*)in)[2 * i + 1];
        u16x8 o;
#pragma unroll
        for (int j = 0; j < 4; ++j) { o[j] = f2bf(a[j]); o[4 + j] = f2bf(b[j]); }
        ((u16x8*)out)[i] = o;
    }
}

// ---------------------------------------------------------------------------
// Pure-bf16 GEMM, m97 structure: C[M][N] = A[M][K] @ B[N][K]^T.
// 128x128 tile, BK=32, 4 waves (2x2 of 64x64), mfma_f32_16x16x32_bf16.
// Staging via global_load_lds dwordx4 into linear (unpadded) [128][32] LDS.
// 2 barriers per K-step; fragments via ds_read_b128.
// ---------------------------------------------------------------------------
template<bool OUT_F32>
__global__ __launch_bounds__(256, 2)
void gemm_bb(const u16* __restrict__ A, const u16* __restrict__ B,
             void* __restrict__ Cv, int M, int N, int K) {
    __shared__ __align__(16) u16 As[128 * 32];
    __shared__ __align__(16) u16 Bs[128 * 32];
    const int tid  = threadIdx.x;
    const int wave = tid >> 6, lane = tid & 63;
    const int lr = lane & 15, quad = lane >> 4;
    const int m0 = blockIdx.y * 128, n0 = blockIdx.x * 128;
    const int wr = (wave >> 1) * 64, wc = (wave & 1) * 64;

    // staging map: 4 threads/row, 8 bf16 (16B) each; issue covers rows 0..63,
    // second issue rows 64..127. LDS dest byte = tid*16 (+4096) — linear, and
    // exactly wave-uniform-base + lane*16 as global_load_lds requires.
    const int srow = tid >> 2;         // 0..63
    const int scol = (tid & 3) * 8;    // 0,8,16,24 (u16 units)
    const u16* ag = A + (size_t)(m0 + srow) * K + scol;
    const u16* bg = B + (size_t)(n0 + srow) * K + scol;
    const size_t rowskip = (size_t)64 * K;
    u16* asl = As + wave * 512;        // per-wave uniform LDS base (u16 units)
    u16* bsl = Bs + wave * 512;

    f32x4 acc[4][4] = {};

    for (int k0 = 0; k0 < K; k0 += 32) {
        __syncthreads();  // previous iteration's fragment reads complete
        GLL16(ag + k0,           asl);
        GLL16(ag + rowskip + k0, asl + 2048);
        GLL16(bg + k0,           bsl);
        GLL16(bg + rowskip + k0, bsl + 2048);
        __syncthreads();  // compiler drains vmcnt(0) before s_barrier

        bf16x8 af[4], bfv[4];
#pragma unroll
        for (int i = 0; i < 4; ++i)
            af[i] = *(const bf16x8*)(As + (wr + i * 16 + lr) * 32 + quad * 8);
#pragma unroll
        for (int j = 0; j < 4; ++j)
            bfv[j] = *(const bf16x8*)(Bs + (wc + j * 16 + lr) * 32 + quad * 8);
#pragma unroll
        for (int i = 0; i < 4; ++i)
#pragma unroll
            for (int j = 0; j < 4; ++j)
                acc[i][j] = MFMA16(af[i], bfv[j], acc[i][j]);
    }

    // epilogue: C/D layout col=lane&15, row=quad*4+reg
#pragma unroll
    for (int i = 0; i < 4; ++i) {
#pragma unroll
        for (int r = 0; r < 4; ++r) {
            int row = m0 + wr + i * 16 + quad * 4 + r;
#pragma unroll
            for (int j = 0; j < 4; ++j) {
                int col = n0 + wc + j * 16 + lr;
                if (OUT_F32)
                    ((float*)Cv)[(size_t)row * N + col] = acc[i][j][r];
                else
                    ((u16*)Cv)[(size_t)row * N + col] = f2bf(acc[i][j][r]);
            }
        }
    }
}

// ---------------------------------------------------------------------------
// Legacy mixed GEMM (A bf16 or f32, W f32 converted during staging).
// Kept only as the O-projection fallback when ws_size < 64 MB.
// ---------------------------------------------------------------------------
template<bool A_BF16, bool OUT_F32>
__global__ __launch_bounds__(256, 2)
void gemm_bt(const void* __restrict__ Av, const float* __restrict__ W,
             void* __restrict__ Cv, int M, int N, int K) {
    __shared__ __align__(16) u16 As[128 * 40];
    __shared__ __align__(16) u16 Bs[128 * 40];
    const int tid  = threadIdx.x;
    const int wave = tid >> 6, lane = tid & 63;
    const int lr = lane & 15, quad = lane >> 4;
    const int m0 = blockIdx.y * 128, n0 = blockIdx.x * 128;
    const int wr = (wave >> 1) * 64, wc = (wave & 1) * 64;

    const int r8 = tid >> 3;
    const int c4 = (tid & 7) * 4;
    const int r4 = tid >> 2;
    const int c8 = (tid & 3) * 8;

    f32x4 acc[4][4] = {};

    for (int k0 = 0; k0 < K; k0 += 32) {
        f32x4 wreg[4];
#pragma unroll
        for (int rep = 0; rep < 4; ++rep)
            wreg[rep] = *(const f32x4*)(W + (size_t)(n0 + rep * 32 + r8) * K + k0 + c4);
        f32x4 aregf[4];
        u16x8 aregb[2];
        if (A_BF16) {
#pragma unroll
            for (int rep = 0; rep < 2; ++rep)
                aregb[rep] = *(const u16x8*)((const u16*)Av + (size_t)(m0 + rep * 64 + r4) * K + k0 + c8);
        } else {
#pragma unroll
            for (int rep = 0; rep < 4; ++rep)
                aregf[rep] = *(const f32x4*)((const float*)Av + (size_t)(m0 + rep * 32 + r8) * K + k0 + c4);
        }
        __syncthreads();
#pragma unroll
        for (int rep = 0; rep < 4; ++rep)
            *(u16x4*)(Bs + (rep * 32 + r8) * 40 + c4) = cvt4(wreg[rep]);
        if (A_BF16) {
#pragma unroll
            for (int rep = 0; rep < 2; ++rep)
                *(u16x8*)(As + (rep * 64 + r4) * 40 + c8) = aregb[rep];
        } else {
#pragma unroll
            for (int rep = 0; rep < 4; ++rep)
                *(u16x4*)(As + (rep * 32 + r8) * 40 + c4) = cvt4(aregf[rep]);
        }
        __syncthreads();

        bf16x8 af[4], bfv[4];
#pragma unroll
        for (int i = 0; i < 4; ++i)
            af[i] = *(const bf16x8*)(As + (wr + i * 16 + lr) * 40 + quad * 8);
#pragma unroll
        for (int j = 0; j < 4; ++j)
            bfv[j] = *(const bf16x8*)(Bs + (wc + j * 16 + lr) * 40 + quad * 8);
#pragma unroll
        for (int i = 0; i < 4; ++i)
#pragma unroll
            for (int j = 0; j < 4; ++j)
                acc[i][j] = MFMA16(af[i], bfv[j], acc[i][j]);
    }

#pragma unroll
    for (int i = 0; i < 4; ++i) {
#pragma unroll
        for (int r = 0; r < 4; ++r) {
            int row = m0 + wr + i * 16 + quad * 4 + r;
#pragma unroll
            for (int j = 0; j < 4; ++j) {
                int col = n0 + wc + j * 16 + lr;
                if (OUT_F32)
                    ((float*)Cv)[(size_t)row * N + col] = acc[i][j][r];
                else
                    ((u16*)Cv)[(size_t)row * N + col] = f2bf(acc[i][j][r]);
            }
        }
    }
}

// ---------------------------------------------------------------------------
// RoPE in-place on bf16 q [4096][32*128] and k [4096][8*128], interleaved
// pairs. cos/sin computed inline in fp32.
// ---------------------------------------------------------------------------
__global__ void rope_k(u16* __restrict__ q, u16* __restrict__ kk) {
    const int QP = 2 * 2048 * 32 * 64;  // 8388608
    const int KP = 2 * 2048 * 8 * 64;   // 2097152
    int idx = blockIdx.x * 256 + threadIdx.x;
    u16* ptr;
    int s, i;
    if (idx < QP) {
        i = idx & 63;
        int h = (idx >> 6) & 31;
        int m = idx >> 11;
        s = m & 2047;
        ptr = q + (size_t)m * 4096 + h * 128 + 2 * i;
    } else {
        idx -= QP;
        if (idx >= KP) return;
        i = idx & 63;
        int h = (idx >> 6) & 7;
        int m = idx >> 9;
        s = m & 2047;
        ptr = kk + (size_t)m * 1024 + h * 128 + 2 * i;
    }
    float inv = expf(-9.210340371976184f * (float)(2 * i) * (1.0f / 128.0f));
    float ang = (float)s * inv;
    float sn = sinf(ang);
    float c  = cosf(ang);
    u16x2 v = *(u16x2*)ptr;
    float tr = bf2f(v[0]), ti = bf2f(v[1]);
    u16x2 o;
    o[0] = f2bf(tr * c - ti * sn);
    o[1] = f2bf(tr * sn + ti * c);
    *(u16x2*)ptr = o;
}

// ---------------------------------------------------------------------------
// Flash attention, causal, GQA rep=4, bf16 in/out. grid (S/64, H, B).
// Wave w owns q rows [qb*64 + w*16, +16). O aliases Q (per-block region is
// read before written, disjoint across blocks) -> no restrict on Q/O.
// ---------------------------------------------------------------------------
__global__ __launch_bounds__(256, 2)
void flash_attn(const u16* Q, const u16* __restrict__ K,
                const u16* __restrict__ V, u16* O) {
    __shared__ __align__(16) u16 Ks[64 * 136];
    __shared__ __align__(16) u16 Vt[128 * 72];
    __shared__ __align__(16) u16 Ps[4 * 16 * 72];
    const int   S     = 2048;
    const float scale = 0.08838834764831845f;  // 128^-0.5
    const int tid  = threadIdx.x;
    const int wave = tid >> 6, lane = tid & 63;
    const int lr = lane & 15, quad = lane >> 4;
    const int qb = blockIdx.x, h = blockIdx.y, b = blockIdx.z;
    const int hk  = h >> 2;
    const int bS  = b * S;
    const int qg0 = qb * 64;

    bf16x8 qf[4];
    {
        const u16* qp = Q + (size_t)(bS + qg0 + wave * 16 + lr) * 4096 + h * 128 + quad * 8;
#pragma unroll
        for (int kc = 0; kc < 4; ++kc) qf[kc] = *(const bf16x8*)(qp + kc * 32);
    }

    f32x4 o[8] = {};
    float mrow[4] = {-1e30f, -1e30f, -1e30f, -1e30f};
    float lrow[4] = {0.f, 0.f, 0.f, 0.f};

    const int vk = tid & 63;

    for (int kt = 0; kt <= qb; ++kt) {
        u16x8 kreg[4], vreg[4];
#pragma unroll
        for (int c = 0; c < 4; ++c) {
            int idx = c * 256 + tid;
            int row = idx >> 4, pos = (idx & 15) * 8;
            kreg[c] = *(const u16x8*)(K + (size_t)(bS + kt * 64 + row) * 1024 + hk * 128 + pos);
            int d0 = (c * 4 + (tid >> 6)) * 8;
            vreg[c] = *(const u16x8*)(V + (size_t)(bS + kt * 64 + vk) * 1024 + hk * 128 + d0);
        }
        __syncthreads();
#pragma unroll
        for (int c = 0; c < 4; ++c) {
            int idx = c * 256 + tid;
            int row = idx >> 4, pos = (idx & 15) * 8;
            *(u16x8*)(Ks + row * 136 + pos) = kreg[c];
            int d0 = (c * 4 + (tid >> 6)) * 8;
#pragma unroll
            for (int j = 0; j < 8; ++j) Vt[(d0 + j) * 72 + vk] = vreg[c][j];
        }
        __syncthreads();

        f32x4 sc[4] = {};
#pragma unroll
        for (int t = 0; t < 4; ++t) {
            int key = t * 16 + lr;
#pragma unroll
            for (int kc = 0; kc < 4; ++kc) {
                bf16x8 kf = *(const bf16x8*)(Ks + key * 136 + (kc * 4 + quad) * 8);
                sc[t] = MFMA16(qf[kc], kf, sc[t]);
            }
        }

        const bool diag = (kt == qb);
#pragma unroll
        for (int t = 0; t < 4; ++t) {
#pragma unroll
            for (int r = 0; r < 4; ++r) {
                float sv = sc[t][r] * scale;
                if (diag) {
                    int key = kt * 64 + t * 16 + lr;
                    int qg  = qg0 + wave * 16 + quad * 4 + r;
                    if (key > qg) sv = -1e30f;
                }
                sc[t][r] = sv;
            }
        }

        float alpha[4];
#pragma unroll
        for (int r = 0; r < 4; ++r) {
            float mx = fmaxf(fmaxf(sc[0][r], sc[1][r]), fmaxf(sc[2][r], sc[3][r]));
#pragma unroll
            for (int d = 1; d < 16; d <<= 1) mx = fmaxf(mx, __shfl_xor(mx, d, 64));
            float mn = fmaxf(mrow[r], mx);
            alpha[r] = __expf(mrow[r] - mn);
            mrow[r]  = mn;
            float rs = 0.f;
#pragma unroll
            for (int t = 0; t < 4; ++t) {
                float e = __expf(sc[t][r] - mn);
                sc[t][r] = e;
                rs += e;
            }
#pragma unroll
            for (int d = 1; d < 16; d <<= 1) rs += __shfl_xor(rs, d, 64);
            lrow[r] = lrow[r] * alpha[r] + rs;
        }
#pragma unroll
        for (int nt = 0; nt < 8; ++nt)
#pragma unroll
            for (int r = 0; r < 4; ++r) o[nt][r] *= alpha[r];

        u16* Pw = Ps + wave * (16 * 72);
#pragma unroll
        for (int t = 0; t < 4; ++t)
#pragma unroll
            for (int r = 0; r < 4; ++r)
                Pw[(quad * 4 + r) * 72 + t * 16 + lr] = f2bf(sc[t][r]);

        bf16x8 pa[2];
#pragma unroll
        for (int c = 0; c < 2; ++c)
            pa[c] = *(const bf16x8*)(Pw + lr * 72 + c * 32 + quad * 8);

#pragma unroll
        for (int nt = 0; nt < 8; ++nt) {
#pragma unroll
            for (int c = 0; c < 2; ++c) {
                bf16x8 bv = *(const bf16x8*)(Vt + (nt * 16 + lr) * 72 + c * 32 + quad * 8);
                o[nt] = MFMA16(pa[c], bv, o[nt]);
            }
        }
    }

    float inv[4];
#pragma unroll
    for (int r = 0; r < 4; ++r) inv[r] = 1.0f / lrow[r];
#pragma unroll
    for (int nt = 0; nt < 8; ++nt) {
#pragma unroll
        for (int r = 0; r < 4; ++r) {
            int tok = bS + qg0 + wave * 16 + quad * 4 + r;
            int col = h * 128 + nt * 16 + lr;
            O[(size_t)tok * 4096 + col] = f2bf(o[nt][r] * inv[r]);
        }
    }
}

// ---------------------------------------------------------------------------
extern "C" void kernel_launch(void* const* d_in, const int* in_sizes, int n_in,
                              void* d_out, int out_size, void* d_ws, size_t ws_size,
                              hipStream_t stream) {
    const float* x  = (const float*)d_in[0];
    // d_in[1..4] (freqs_cos, freqs_sin, positions, mask) unused: rope freqs
    // computed inline in fp32; causal mask hardcoded.
    const float* wq = (const float*)d_in[5];
    const float* wk = (const float*)d_in[6];
    const float* wv = (const float*)d_in[7];
    const float* wo = (const float*)d_in[8];
    float* out = (float*)d_out;

    // Workspace plan (all bf16 scratch):
    //   d_ws[ 0:32MB) qws  : Q projection [4096][4096]; flash O aliases it.
    //   d_ws[32:64MB) wob  : bf16 wo (only if ws_size >= 64MB; else fallback).
    //   d_out (64MB f32, dead until final GEMM writes it):
    //     [ 0:32MB) xb            : bf16 x [4096][4096]
    //     [32:64MB) wqb           : bf16 wq — dead after Q proj, then reused:
    //     [32:40MB) wkb  [40:48MB) wvb  [48:56MB) kws  [56:64MB) vws
    u16* qws = (u16*)d_ws;
    u16* xb  = (u16*)d_out;
    u16* wqb = xb + (32u << 20) / 2;
    u16* wkb = wqb;
    u16* wvb = wkb + (8u << 20) / 2;
    u16* kws = wvb + (8u << 20) / 2;
    u16* vws = kws + (8u << 20) / 2;

    dim3 blk(256);
    cvt_bf16<<<dim3(2048), blk, 0, stream>>>(x,  xb,  2097152);
    cvt_bf16<<<dim3(2048), blk, 0, stream>>>(wq, wqb, 2097152);
    gemm_bb<false><<<dim3(32, 32), blk, 0, stream>>>(xb, wqb, qws, 4096, 4096, 4096);
    cvt_bf16<<<dim3(1024), blk, 0, stream>>>(wk, wkb, 524288);
    cvt_bf16<<<dim3(1024), blk, 0, stream>>>(wv, wvb, 524288);
    gemm_bb<false><<<dim3(8, 32), blk, 0, stream>>>(xb, wkb, kws, 4096, 1024, 4096);
    gemm_bb<false><<<dim3(8, 32), blk, 0, stream>>>(xb, wvb, vws, 4096, 1024, 4096);
    rope_k<<<dim3(40960), blk, 0, stream>>>(qws, kws);
    flash_attn<<<dim3(32, 32, 2), blk, 0, stream>>>(qws, kws, vws, qws);
    if (ws_size >= (size_t)(64u << 20)) {
        u16* wob = qws + (32u << 20) / 2;
        cvt_bf16<<<dim3(2048), blk, 0, stream>>>(wo, wob, 2097152);
        gemm_bb<true><<<dim3(32, 32), blk, 0, stream>>>(qws, wob, out, 4096, 4096, 4096);
    } else {
        gemm_bt<true, true><<<dim3(32, 32), blk, 0, stream>>>(qws, wo, out, 4096, 4096, 4096);
    }
}

// Round 2
// 1025.325 us; speedup vs baseline: 1.9603x; 1.0490x over previous
//
#include <hip/hip_runtime.h>
#include <math.h>

typedef unsigned short u16;
typedef short bf16x8 __attribute__((ext_vector_type(8)));
typedef float f32x4 __attribute__((ext_vector_type(4)));
typedef u16 u16x2 __attribute__((ext_vector_type(2)));
typedef u16 u16x4 __attribute__((ext_vector_type(4)));
typedef u16 u16x8 __attribute__((ext_vector_type(8)));

#define MFMA16(a, b, c) __builtin_amdgcn_mfma_f32_16x16x32_bf16(a, b, c, 0, 0, 0)

// direct global->LDS async copy, 16B per lane; dest = wave-uniform base + lane*16
#define GLL16(g, l)                                                  \
    __builtin_amdgcn_global_load_lds(                                \
        (__attribute__((address_space(1))) void*)(g),                \
        (__attribute__((address_space(3))) void*)(l), 16, 0, 0)

__device__ __forceinline__ float bf2f(u16 u) {
    union { unsigned int i; float f; } v;
    v.i = ((unsigned int)u) << 16;
    return v.f;
}
__device__ __forceinline__ u16 f2bf(float f) {
    union { float f; unsigned int i; } v;
    v.f = f;
    unsigned int r = (v.i + 0x7FFFu + ((v.i >> 16) & 1u)) >> 16;
    return (u16)r;
}
__device__ __forceinline__ u16x4 cvt4(f32x4 v) {
    u16x4 r;
#pragma unroll
    for (int j = 0; j < 4; ++j) r[j] = f2bf(v[j]);
    return r;
}

// ---------------------------------------------------------------------------
// Elementwise f32 -> bf16 (RNE), 8 elems/thread/iter, grid-stride.
// ---------------------------------------------------------------------------
__global__ __launch_bounds__(256)
void cvt_bf16(const float* __restrict__ in, u16* __restrict__ out, int n8) {
    int i = blockIdx.x * 256 + threadIdx.x;
    const int stride = gridDim.x * 256;
    for (; i < n8; i += stride) {
        f32x4 a = ((const f32x4*)in)[2 * i];
        f32x4 b = ((const f32x4*)in)[2 * i + 1];
        u16x8 o;
#pragma unroll
        for (int j = 0; j < 4; ++j) { o[j] = f2bf(a[j]); o[4 + j] = f2bf(b[j]); }
        ((u16x8*)out)[i] = o;
    }
}

// ---------------------------------------------------------------------------
// Pure-bf16 GEMM, m97 structure: C[M][N] = A[M][K] @ B[N][K]^T.
// 128x128 tile, BK=32, 4 waves (2x2 of 64x64), mfma_f32_16x16x32_bf16.
// Staging via global_load_lds dwordx4 into linear [128][32] LDS.
// OUT_TRANS: write C transposed as Ct[N][M] (u16x4 per lane, bf16) — used to
// produce V^T for the flash kernel (V needs no RoPE).
// ---------------------------------------------------------------------------
template<bool OUT_F32, bool OUT_TRANS>
__global__ __launch_bounds__(256, 2)
void gemm_bb(const u16* __restrict__ A, const u16* __restrict__ B,
             void* __restrict__ Cv, int M, int N, int K) {
    __shared__ __align__(16) u16 As[128 * 32];
    __shared__ __align__(16) u16 Bs[128 * 32];
    const int tid  = threadIdx.x;
    const int wave = tid >> 6, lane = tid & 63;
    const int lr = lane & 15, quad = lane >> 4;
    const int m0 = blockIdx.y * 128, n0 = blockIdx.x * 128;
    const int wr = (wave >> 1) * 64, wc = (wave & 1) * 64;

    const int srow = tid >> 2;         // 0..63
    const int scol = (tid & 3) * 8;    // 0,8,16,24 (u16 units)
    const u16* ag = A + (size_t)(m0 + srow) * K + scol;
    const u16* bg = B + (size_t)(n0 + srow) * K + scol;
    const size_t rowskip = (size_t)64 * K;
    u16* asl = As + wave * 512;        // per-wave uniform LDS base (u16 units)
    u16* bsl = Bs + wave * 512;

    f32x4 acc[4][4] = {};

    for (int k0 = 0; k0 < K; k0 += 32) {
        __syncthreads();
        GLL16(ag + k0,           asl);
        GLL16(ag + rowskip + k0, asl + 2048);
        GLL16(bg + k0,           bsl);
        GLL16(bg + rowskip + k0, bsl + 2048);
        __syncthreads();

        bf16x8 af[4], bfv[4];
#pragma unroll
        for (int i = 0; i < 4; ++i)
            af[i] = *(const bf16x8*)(As + (wr + i * 16 + lr) * 32 + quad * 8);
#pragma unroll
        for (int j = 0; j < 4; ++j)
            bfv[j] = *(const bf16x8*)(Bs + (wc + j * 16 + lr) * 32 + quad * 8);
#pragma unroll
        for (int i = 0; i < 4; ++i)
#pragma unroll
            for (int j = 0; j < 4; ++j)
                acc[i][j] = MFMA16(af[i], bfv[j], acc[i][j]);
    }

    if (OUT_TRANS) {
        // Ct[N][M] bf16: lane stores 4 consecutive tokens (acc reg dim) per (i,j)
#pragma unroll
        for (int i = 0; i < 4; ++i) {
            int row0 = m0 + wr + i * 16 + quad * 4;
#pragma unroll
            for (int j = 0; j < 4; ++j) {
                int col = n0 + wc + j * 16 + lr;
                *(u16x4*)((u16*)Cv + (size_t)col * M + row0) = cvt4(acc[i][j]);
            }
        }
        return;
    }
#pragma unroll
    for (int i = 0; i < 4; ++i) {
#pragma unroll
        for (int r = 0; r < 4; ++r) {
            int row = m0 + wr + i * 16 + quad * 4 + r;
#pragma unroll
            for (int j = 0; j < 4; ++j) {
                int col = n0 + wc + j * 16 + lr;
                if (OUT_F32)
                    ((float*)Cv)[(size_t)row * N + col] = acc[i][j][r];
                else
                    ((u16*)Cv)[(size_t)row * N + col] = f2bf(acc[i][j][r]);
            }
        }
    }
}

// ---------------------------------------------------------------------------
// Legacy mixed GEMM — O-projection fallback when ws_size < 64 MB.
// ---------------------------------------------------------------------------
template<bool A_BF16, bool OUT_F32>
__global__ __launch_bounds__(256, 2)
void gemm_bt(const void* __restrict__ Av, const float* __restrict__ W,
             void* __restrict__ Cv, int M, int N, int K) {
    __shared__ __align__(16) u16 As[128 * 40];
    __shared__ __align__(16) u16 Bs[128 * 40];
    const int tid  = threadIdx.x;
    const int wave = tid >> 6, lane = tid & 63;
    const int lr = lane & 15, quad = lane >> 4;
    const int m0 = blockIdx.y * 128, n0 = blockIdx.x * 128;
    const int wr = (wave >> 1) * 64, wc = (wave & 1) * 64;

    const int r8 = tid >> 3;
    const int c4 = (tid & 7) * 4;
    const int r4 = tid >> 2;
    const int c8 = (tid & 3) * 8;

    f32x4 acc[4][4] = {};

    for (int k0 = 0; k0 < K; k0 += 32) {
        f32x4 wreg[4];
#pragma unroll
        for (int rep = 0; rep < 4; ++rep)
            wreg[rep] = *(const f32x4*)(W + (size_t)(n0 + rep * 32 + r8) * K + k0 + c4);
        f32x4 aregf[4];
        u16x8 aregb[2];
        if (A_BF16) {
#pragma unroll
            for (int rep = 0; rep < 2; ++rep)
                aregb[rep] = *(const u16x8*)((const u16*)Av + (size_t)(m0 + rep * 64 + r4) * K + k0 + c8);
        } else {
#pragma unroll
            for (int rep = 0; rep < 4; ++rep)
                aregf[rep] = *(const f32x4*)((const float*)Av + (size_t)(m0 + rep * 32 + r8) * K + k0 + c4);
        }
        __syncthreads();
#pragma unroll
        for (int rep = 0; rep < 4; ++rep)
            *(u16x4*)(Bs + (rep * 32 + r8) * 40 + c4) = cvt4(wreg[rep]);
        if (A_BF16) {
#pragma unroll
            for (int rep = 0; rep < 2; ++rep)
                *(u16x8*)(As + (rep * 64 + r4) * 40 + c8) = aregb[rep];
        } else {
#pragma unroll
            for (int rep = 0; rep < 4; ++rep)
                *(u16x4*)(As + (rep * 32 + r8) * 40 + c4) = cvt4(aregf[rep]);
        }
        __syncthreads();

        bf16x8 af[4], bfv[4];
#pragma unroll
        for (int i = 0; i < 4; ++i)
            af[i] = *(const bf16x8*)(As + (wr + i * 16 + lr) * 40 + quad * 8);
#pragma unroll
        for (int j = 0; j < 4; ++j)
            bfv[j] = *(const bf16x8*)(Bs + (wc + j * 16 + lr) * 40 + quad * 8);
#pragma unroll
        for (int i = 0; i < 4; ++i)
#pragma unroll
            for (int j = 0; j < 4; ++j)
                acc[i][j] = MFMA16(af[i], bfv[j], acc[i][j]);
    }

#pragma unroll
    for (int i = 0; i < 4; ++i) {
#pragma unroll
        for (int r = 0; r < 4; ++r) {
            int row = m0 + wr + i * 16 + quad * 4 + r;
#pragma unroll
            for (int j = 0; j < 4; ++j) {
                int col = n0 + wc + j * 16 + lr;
                if (OUT_F32)
                    ((float*)Cv)[(size_t)row * N + col] = acc[i][j][r];
                else
                    ((u16*)Cv)[(size_t)row * N + col] = f2bf(acc[i][j][r]);
            }
        }
    }
}

// ---------------------------------------------------------------------------
// RoPE in-place on bf16 q [4096][32*128] and k [4096][8*128] (V untouched).
// ---------------------------------------------------------------------------
__global__ void rope_k(u16* __restrict__ q, u16* __restrict__ kk) {
    const int QP = 2 * 2048 * 32 * 64;  // 8388608
    const int KP = 2 * 2048 * 8 * 64;   // 2097152
    int idx = blockIdx.x * 256 + threadIdx.x;
    u16* ptr;
    int s, i;
    if (idx < QP) {
        i = idx & 63;
        int h = (idx >> 6) & 31;
        int m = idx >> 11;
        s = m & 2047;
        ptr = q + (size_t)m * 4096 + h * 128 + 2 * i;
    } else {
        idx -= QP;
        if (idx >= KP) return;
        i = idx & 63;
        int h = (idx >> 6) & 7;
        int m = idx >> 9;
        s = m & 2047;
        ptr = kk + (size_t)m * 1024 + h * 128 + 2 * i;
    }
    float inv = expf(-9.210340371976184f * (float)(2 * i) * (1.0f / 128.0f));
    float ang = (float)s * inv;
    float sn = sinf(ang);
    float c  = cosf(ang);
    u16x2 v = *(u16x2*)ptr;
    float tr = bf2f(v[0]), ti = bf2f(v[1]);
    u16x2 o;
    o[0] = f2bf(tr * c - ti * sn);
    o[1] = f2bf(tr * sn + ti * c);
    *(u16x2*)ptr = o;
}

// ---------------------------------------------------------------------------
// Flash attention, causal, GQA rep=4, bf16 in/out. grid (S/64, H, B).
// K staged row-major [64][128] u16 via global_load_lds; V staged from the
// pre-transposed Vt_g [1024][4096] as [128 d][64 key] u16. Both LDS tiles use
// a 16B-chunk XOR swizzle (chunk ^= row&7) realized as linear LDS dest +
// inverse-swizzled GLOBAL source (rule #21), read back with the same XOR ->
// conflict-free ds_read_b128 on both QK and PV paths.
// qb reversed so heavy causal blocks dispatch first.
// ---------------------------------------------------------------------------
__global__ __launch_bounds__(256, 3)
void flash_attn(const u16* Q, const u16* __restrict__ K,
                const u16* __restrict__ Vt_g, u16* O) {
    __shared__ __align__(16) u16 Ks[64 * 128];   // swizzled 256B rows
    __shared__ __align__(16) u16 Vs[128 * 64];   // V^T, swizzled 128B rows
    __shared__ __align__(16) u16 Ps[4 * 16 * 72];
    const float scale = 0.08838834764831845f;  // 128^-0.5
    const int tid  = threadIdx.x;
    const int wave = tid >> 6, lane = tid & 63;
    const int lr = lane & 15, quad = lane >> 4;
    const int qb = (int)gridDim.x - 1 - (int)blockIdx.x;  // heavy blocks first
    const int h = blockIdx.y, b = blockIdx.z;
    const int hk  = h >> 2;
    const int bS  = b * 2048;
    const int qg0 = qb * 64;

    bf16x8 qf[4];
    {
        const u16* qp = Q + (size_t)(bS + qg0 + wave * 16 + lr) * 4096 + h * 128 + quad * 8;
#pragma unroll
        for (int kc = 0; kc < 4; ++kc) qf[kc] = *(const bf16x8*)(qp + kc * 32);
    }

    f32x4 o[8] = {};
    float mrow[4] = {-1e30f, -1e30f, -1e30f, -1e30f};
    float lrow[4] = {0.f, 0.f, 0.f, 0.f};

    // --- staging source lanes (inverse-swizzled global addresses) ---
    // K: dest byte = it*4096 + tid*16 -> row key = it*16 + (tid>>4),
    //    chunk p = tid&15 holds global d-chunk p ^ (key&7).
    const int ktr = tid >> 4;                       // 0..15
    const int kd  = ((tid & 15) ^ (ktr & 7)) * 8;   // d offset (u16)
    const u16* kg = K + (size_t)(bS + ktr) * 1024 + hk * 128 + kd;
    // V^T: dest byte = it*4096 + tid*16 -> row d = it*32 + (tid>>3),
    //    chunk p = tid&7 holds global key-chunk p ^ (d&7).
    const int vdr = tid >> 3;                       // 0..31
    const int vk0 = ((tid & 7) ^ (vdr & 7)) * 8;    // key offset (u16)
    const u16* vg = Vt_g + (size_t)(hk * 128 + vdr) * 4096 + bS + vk0;
    u16* kl = Ks + wave * 512;                      // uniform per-wave base
    u16* vl = Vs + wave * 512;

    for (int kt = 0; kt <= qb; ++kt) {
        __syncthreads();  // previous iteration's LDS reads complete
        {
            const u16* kgk = kg + (size_t)(kt * 64) * 1024;
            const u16* vgk = vg + kt * 64;
#pragma unroll
            for (int it = 0; it < 4; ++it) {
                GLL16(kgk + (size_t)(it * 16) * 1024, kl + it * 2048);
                GLL16(vgk + (size_t)(it * 32) * 4096, vl + it * 2048);
            }
        }
        __syncthreads();  // vmcnt(0) drained before barrier

        f32x4 sc[4] = {};
#pragma unroll
        for (int t = 0; t < 4; ++t) {
            int key = t * 16 + lr;
#pragma unroll
            for (int kc = 0; kc < 4; ++kc) {
                bf16x8 kf = *(const bf16x8*)(Ks + key * 128 + (((kc * 4 + quad) ^ (lr & 7)) << 3));
                sc[t] = MFMA16(qf[kc], kf, sc[t]);
            }
        }

        const bool diag = (kt == qb);
#pragma unroll
        for (int t = 0; t < 4; ++t) {
#pragma unroll
            for (int r = 0; r < 4; ++r) {
                float sv = sc[t][r] * scale;
                if (diag) {
                    int key = kt * 64 + t * 16 + lr;
                    int qg  = qg0 + wave * 16 + quad * 4 + r;
                    if (key > qg) sv = -1e30f;
                }
                sc[t][r] = sv;
            }
        }

        float alpha[4];
#pragma unroll
        for (int r = 0; r < 4; ++r) {
            float mx = fmaxf(fmaxf(sc[0][r], sc[1][r]), fmaxf(sc[2][r], sc[3][r]));
#pragma unroll
            for (int d = 1; d < 16; d <<= 1) mx = fmaxf(mx, __shfl_xor(mx, d, 64));
            float mn = fmaxf(mrow[r], mx);
            alpha[r] = __expf(mrow[r] - mn);
            mrow[r]  = mn;
            float rs = 0.f;
#pragma unroll
            for (int t = 0; t < 4; ++t) {
                float e = __expf(sc[t][r] - mn);
                sc[t][r] = e;
                rs += e;
            }
#pragma unroll
            for (int d = 1; d < 16; d <<= 1) rs += __shfl_xor(rs, d, 64);
            lrow[r] = lrow[r] * alpha[r] + rs;
        }
#pragma unroll
        for (int nt = 0; nt < 8; ++nt)
#pragma unroll
            for (int r = 0; r < 4; ++r) o[nt][r] *= alpha[r];

        u16* Pw = Ps + wave * (16 * 72);
#pragma unroll
        for (int t = 0; t < 4; ++t)
#pragma unroll
            for (int r = 0; r < 4; ++r)
                Pw[(quad * 4 + r) * 72 + t * 16 + lr] = f2bf(sc[t][r]);

        bf16x8 pa[2];
#pragma unroll
        for (int c = 0; c < 2; ++c)
            pa[c] = *(const bf16x8*)(Pw + lr * 72 + c * 32 + quad * 8);

#pragma unroll
        for (int nt = 0; nt < 8; ++nt) {
#pragma unroll
            for (int c = 0; c < 2; ++c) {
                bf16x8 bv = *(const bf16x8*)(Vs + (nt * 16 + lr) * 64 + (((c * 4 + quad) ^ (lr & 7)) << 3));
                o[nt] = MFMA16(pa[c], bv, o[nt]);
            }
        }
    }

    float inv[4];
#pragma unroll
    for (int r = 0; r < 4; ++r) inv[r] = 1.0f / lrow[r];
#pragma unroll
    for (int nt = 0; nt < 8; ++nt) {
#pragma unroll
        for (int r = 0; r < 4; ++r) {
            int tok = bS + qg0 + wave * 16 + quad * 4 + r;
            int col = h * 128 + nt * 16 + lr;
            O[(size_t)tok * 4096 + col] = f2bf(o[nt][r] * inv[r]);
        }
    }
}

// ---------------------------------------------------------------------------
extern "C" void kernel_launch(void* const* d_in, const int* in_sizes, int n_in,
                              void* d_out, int out_size, void* d_ws, size_t ws_size,
                              hipStream_t stream) {
    const float* x  = (const float*)d_in[0];
    const float* wq = (const float*)d_in[5];
    const float* wk = (const float*)d_in[6];
    const float* wv = (const float*)d_in[7];
    const float* wo = (const float*)d_in[8];
    float* out = (float*)d_out;

    // Workspace plan (all bf16 scratch):
    //   d_ws[ 0:32MB) qws  : Q projection [4096][4096]; flash O aliases it.
    //   d_ws[32:64MB) wob  : bf16 wo (only if ws_size >= 64MB; else fallback).
    //   d_out (64MB f32, dead until final GEMM writes it):
    //     [ 0:32MB) xb   : bf16 x [4096][4096]
    //     [32:64MB) wqb  : bf16 wq — dead after Q proj, then reused:
    //     [32:40MB) wkb  [40:48MB) wvb  [48:56MB) kws  [56:64MB) vtws
    u16* qws  = (u16*)d_ws;
    u16* xb   = (u16*)d_out;
    u16* wqb  = xb + (32u << 20) / 2;
    u16* wkb  = wqb;
    u16* wvb  = wkb + (8u << 20) / 2;
    u16* kws  = wvb + (8u << 20) / 2;
    u16* vtws = kws + (8u << 20) / 2;   // V^T [1024][4096] bf16

    dim3 blk(256);
    cvt_bf16<<<dim3(2048), blk, 0, stream>>>(x,  xb,  2097152);
    cvt_bf16<<<dim3(2048), blk, 0, stream>>>(wq, wqb, 2097152);
    gemm_bb<false, false><<<dim3(32, 32), blk, 0, stream>>>(xb, wqb, qws, 4096, 4096, 4096);
    cvt_bf16<<<dim3(1024), blk, 0, stream>>>(wk, wkb, 524288);
    cvt_bf16<<<dim3(1024), blk, 0, stream>>>(wv, wvb, 524288);
    gemm_bb<false, false><<<dim3(8, 32), blk, 0, stream>>>(xb, wkb, kws, 4096, 1024, 4096);
    gemm_bb<false, true ><<<dim3(8, 32), blk, 0, stream>>>(xb, wvb, vtws, 4096, 1024, 4096);
    rope_k<<<dim3(40960), blk, 0, stream>>>(qws, kws);
    flash_attn<<<dim3(32, 32, 2), blk, 0, stream>>>(qws, kws, vtws, qws);
    if (ws_size >= (size_t)(64u << 20)) {
        u16* wob = qws + (32u << 20) / 2;
        cvt_bf16<<<dim3(2048), blk, 0, stream>>>(wo, wob, 2097152);
        gemm_bb<true, false><<<dim3(32, 32), blk, 0, stream>>>(qws, wob, out, 4096, 4096, 4096);
    } else {
        gemm_bt<true, true><<<dim3(32, 32), blk, 0, stream>>>(qws, wo, out, 4096, 4096, 4096);
    }
}

// Round 3
// 1023.174 us; speedup vs baseline: 1.9645x; 1.0021x over previous
//
#include <hip/hip_runtime.h>
#include <math.h>

typedef unsigned short u16;
typedef short bf16x8 __attribute__((ext_vector_type(8)));
typedef float f32x4 __attribute__((ext_vector_type(4)));
typedef u16 u16x2 __attribute__((ext_vector_type(2)));
typedef u16 u16x4 __attribute__((ext_vector_type(4)));
typedef u16 u16x8 __attribute__((ext_vector_type(8)));

#define MFMA16(a, b, c) __builtin_amdgcn_mfma_f32_16x16x32_bf16(a, b, c, 0, 0, 0)

// direct global->LDS async copy, 16B per lane; dest = wave-uniform base + lane*16
#define GLL16(g, l)                                                  \
    __builtin_amdgcn_global_load_lds(                                \
        (__attribute__((address_space(1))) void*)(g),                \
        (__attribute__((address_space(3))) void*)(l), 16, 0, 0)

__device__ __forceinline__ float bf2f(u16 u) {
    union { unsigned int i; float f; } v;
    v.i = ((unsigned int)u) << 16;
    return v.f;
}
__device__ __forceinline__ u16 f2bf(float f) {
    union { float f; unsigned int i; } v;
    v.f = f;
    unsigned int r = (v.i + 0x7FFFu + ((v.i >> 16) & 1u)) >> 16;
    return (u16)r;
}
__device__ __forceinline__ u16x4 cvt4(f32x4 v) {
    u16x4 r;
#pragma unroll
    for (int j = 0; j < 4; ++j) r[j] = f2bf(v[j]);
    return r;
}

// ---------------------------------------------------------------------------
// Elementwise f32 -> bf16 (RNE), 8 elems/thread/iter, grid-stride.
// ---------------------------------------------------------------------------
__global__ __launch_bounds__(256)
void cvt_bf16(const float* __restrict__ in, u16* __restrict__ out, int n8) {
    int i = blockIdx.x * 256 + threadIdx.x;
    const int stride = gridDim.x * 256;
    for (; i < n8; i += stride) {
        f32x4 a = ((const f32x4*)in)[2 * i];
        f32x4 b = ((const f32x4*)in)[2 * i + 1];
        u16x8 o;
#pragma unroll
        for (int j = 0; j < 4; ++j) { o[j] = f2bf(a[j]); o[4 + j] = f2bf(b[j]); }
        ((u16x8*)out)[i] = o;
    }
}

// ---------------------------------------------------------------------------
// Pure-bf16 GEMM, m97 structure: C[M][N] = A[M][K] @ B[N][K]^T.
// 128x128 tile, BK=32, 4 waves (2x2 of 64x64), mfma_f32_16x16x32_bf16.
// Staging via global_load_lds dwordx4 into linear [128][32] LDS.
// OUT_TRANS: write C transposed as Ct[N][M] (u16x4 per lane, bf16) — used to
// produce V^T for the flash kernel (V needs no RoPE).
// ---------------------------------------------------------------------------
template<bool OUT_F32, bool OUT_TRANS>
__global__ __launch_bounds__(256, 2)
void gemm_bb(const u16* __restrict__ A, const u16* __restrict__ B,
             void* __restrict__ Cv, int M, int N, int K) {
    __shared__ __align__(16) u16 As[128 * 32];
    __shared__ __align__(16) u16 Bs[128 * 32];
    const int tid  = threadIdx.x;
    const int wave = tid >> 6, lane = tid & 63;
    const int lr = lane & 15, quad = lane >> 4;
    const int m0 = blockIdx.y * 128, n0 = blockIdx.x * 128;
    const int wr = (wave >> 1) * 64, wc = (wave & 1) * 64;

    const int srow = tid >> 2;         // 0..63
    const int scol = (tid & 3) * 8;    // 0,8,16,24 (u16 units)
    const u16* ag = A + (size_t)(m0 + srow) * K + scol;
    const u16* bg = B + (size_t)(n0 + srow) * K + scol;
    const size_t rowskip = (size_t)64 * K;
    u16* asl = As + wave * 512;        // per-wave uniform LDS base (u16 units)
    u16* bsl = Bs + wave * 512;

    f32x4 acc[4][4] = {};

    for (int k0 = 0; k0 < K; k0 += 32) {
        __syncthreads();
        GLL16(ag + k0,           asl);
        GLL16(ag + rowskip + k0, asl + 2048);
        GLL16(bg + k0,           bsl);
        GLL16(bg + rowskip + k0, bsl + 2048);
        __syncthreads();

        bf16x8 af[4], bfv[4];
#pragma unroll
        for (int i = 0; i < 4; ++i)
            af[i] = *(const bf16x8*)(As + (wr + i * 16 + lr) * 32 + quad * 8);
#pragma unroll
        for (int j = 0; j < 4; ++j)
            bfv[j] = *(const bf16x8*)(Bs + (wc + j * 16 + lr) * 32 + quad * 8);
#pragma unroll
        for (int i = 0; i < 4; ++i)
#pragma unroll
            for (int j = 0; j < 4; ++j)
                acc[i][j] = MFMA16(af[i], bfv[j], acc[i][j]);
    }

    if (OUT_TRANS) {
#pragma unroll
        for (int i = 0; i < 4; ++i) {
            int row0 = m0 + wr + i * 16 + quad * 4;
#pragma unroll
            for (int j = 0; j < 4; ++j) {
                int col = n0 + wc + j * 16 + lr;
                *(u16x4*)((u16*)Cv + (size_t)col * M + row0) = cvt4(acc[i][j]);
            }
        }
        return;
    }
#pragma unroll
    for (int i = 0; i < 4; ++i) {
#pragma unroll
        for (int r = 0; r < 4; ++r) {
            int row = m0 + wr + i * 16 + quad * 4 + r;
#pragma unroll
            for (int j = 0; j < 4; ++j) {
                int col = n0 + wc + j * 16 + lr;
                if (OUT_F32)
                    ((float*)Cv)[(size_t)row * N + col] = acc[i][j][r];
                else
                    ((u16*)Cv)[(size_t)row * N + col] = f2bf(acc[i][j][r]);
            }
        }
    }
}

// ---------------------------------------------------------------------------
// Legacy mixed GEMM — O-projection fallback when ws_size < 64 MB.
// ---------------------------------------------------------------------------
template<bool A_BF16, bool OUT_F32>
__global__ __launch_bounds__(256, 2)
void gemm_bt(const void* __restrict__ Av, const float* __restrict__ W,
             void* __restrict__ Cv, int M, int N, int K) {
    __shared__ __align__(16) u16 As[128 * 40];
    __shared__ __align__(16) u16 Bs[128 * 40];
    const int tid  = threadIdx.x;
    const int wave = tid >> 6, lane = tid & 63;
    const int lr = lane & 15, quad = lane >> 4;
    const int m0 = blockIdx.y * 128, n0 = blockIdx.x * 128;
    const int wr = (wave >> 1) * 64, wc = (wave & 1) * 64;

    const int r8 = tid >> 3;
    const int c4 = (tid & 7) * 4;
    const int r4 = tid >> 2;
    const int c8 = (tid & 3) * 8;

    f32x4 acc[4][4] = {};

    for (int k0 = 0; k0 < K; k0 += 32) {
        f32x4 wreg[4];
#pragma unroll
        for (int rep = 0; rep < 4; ++rep)
            wreg[rep] = *(const f32x4*)(W + (size_t)(n0 + rep * 32 + r8) * K + k0 + c4);
        f32x4 aregf[4];
        u16x8 aregb[2];
        if (A_BF16) {
#pragma unroll
            for (int rep = 0; rep < 2; ++rep)
                aregb[rep] = *(const u16x8*)((const u16*)Av + (size_t)(m0 + rep * 64 + r4) * K + k0 + c8);
        } else {
#pragma unroll
            for (int rep = 0; rep < 4; ++rep)
                aregf[rep] = *(const f32x4*)((const float*)Av + (size_t)(m0 + rep * 32 + r8) * K + k0 + c4);
        }
        __syncthreads();
#pragma unroll
        for (int rep = 0; rep < 4; ++rep)
            *(u16x4*)(Bs + (rep * 32 + r8) * 40 + c4) = cvt4(wreg[rep]);
        if (A_BF16) {
#pragma unroll
            for (int rep = 0; rep < 2; ++rep)
                *(u16x8*)(As + (rep * 64 + r4) * 40 + c8) = aregb[rep];
        } else {
#pragma unroll
            for (int rep = 0; rep < 4; ++rep)
                *(u16x4*)(As + (rep * 32 + r8) * 40 + c4) = cvt4(aregf[rep]);
        }
        __syncthreads();

        bf16x8 af[4], bfv[4];
#pragma unroll
        for (int i = 0; i < 4; ++i)
            af[i] = *(const bf16x8*)(As + (wr + i * 16 + lr) * 40 + quad * 8);
#pragma unroll
        for (int j = 0; j < 4; ++j)
            bfv[j] = *(const bf16x8*)(Bs + (wc + j * 16 + lr) * 40 + quad * 8);
#pragma unroll
        for (int i = 0; i < 4; ++i)
#pragma unroll
            for (int j = 0; j < 4; ++j)
                acc[i][j] = MFMA16(af[i], bfv[j], acc[i][j]);
    }

#pragma unroll
    for (int i = 0; i < 4; ++i) {
#pragma unroll
        for (int r = 0; r < 4; ++r) {
            int row = m0 + wr + i * 16 + quad * 4 + r;
#pragma unroll
            for (int j = 0; j < 4; ++j) {
                int col = n0 + wc + j * 16 + lr;
                if (OUT_F32)
                    ((float*)Cv)[(size_t)row * N + col] = acc[i][j][r];
                else
                    ((u16*)Cv)[(size_t)row * N + col] = f2bf(acc[i][j][r]);
            }
        }
    }
}

// ---------------------------------------------------------------------------
// RoPE in-place on bf16 q [4096][32*128] and k [4096][8*128] (V untouched).
// ---------------------------------------------------------------------------
__global__ void rope_k(u16* __restrict__ q, u16* __restrict__ kk) {
    const int QP = 2 * 2048 * 32 * 64;  // 8388608
    const int KP = 2 * 2048 * 8 * 64;   // 2097152
    int idx = blockIdx.x * 256 + threadIdx.x;
    u16* ptr;
    int s, i;
    if (idx < QP) {
        i = idx & 63;
        int h = (idx >> 6) & 31;
        int m = idx >> 11;
        s = m & 2047;
        ptr = q + (size_t)m * 4096 + h * 128 + 2 * i;
    } else {
        idx -= QP;
        if (idx >= KP) return;
        i = idx & 63;
        int h = (idx >> 6) & 7;
        int m = idx >> 9;
        s = m & 2047;
        ptr = kk + (size_t)m * 1024 + h * 128 + 2 * i;
    }
    float inv = expf(-9.210340371976184f * (float)(2 * i) * (1.0f / 128.0f));
    float ang = (float)s * inv;
    float sn = sinf(ang);
    float c  = cosf(ang);
    u16x2 v = *(u16x2*)ptr;
    float tr = bf2f(v[0]), ti = bf2f(v[1]);
    u16x2 o;
    o[0] = f2bf(tr * c - ti * sn);
    o[1] = f2bf(tr * sn + ti * c);
    *(u16x2*)ptr = o;
}

// ---------------------------------------------------------------------------
// Flash attention, causal, GQA rep=4, bf16 in/out. grid (S/64, H, B).
// Pipelined: double-buffered K/V LDS tiles staged via global_load_lds; tile
// kt+1's loads are issued at the top of iter kt, then `s_waitcnt vmcnt(8)`
// (counted — only tile kt's loads must land; the 8 newest stay in flight
// under QK+softmax+PV). Raw s_barrier (no compiler vmcnt(0) drain).
// Barrier 1 (after vmcnt): tile-kt LDS writes visible to all waves (RAW).
// Barrier 2 (end of iter): all waves done reading buf^1 before the next
// iteration's prefetch overwrites it (WAR).
// Both LDS tiles use a 16B-chunk XOR swizzle (chunk ^= row&7): linear LDS
// dest + inverse-swizzled GLOBAL source (rule #21), read back with same XOR.
// qb reversed so heavy causal blocks dispatch first.
// ---------------------------------------------------------------------------
__global__ __launch_bounds__(256, 2)
void flash_attn(const u16* Q, const u16* __restrict__ K,
                const u16* __restrict__ Vt_g, u16* O) {
    __shared__ __align__(16) u16 Ks[2][64 * 128];   // swizzled 256B rows
    __shared__ __align__(16) u16 Vs[2][128 * 64];   // V^T, swizzled 128B rows
    __shared__ __align__(16) u16 Ps[4 * 16 * 72];
    const float scale = 0.08838834764831845f;  // 128^-0.5
    const int tid  = threadIdx.x;
    const int wave = tid >> 6, lane = tid & 63;
    const int lr = lane & 15, quad = lane >> 4;
    const int qb = (int)gridDim.x - 1 - (int)blockIdx.x;  // heavy blocks first
    const int h = blockIdx.y, b = blockIdx.z;
    const int hk  = h >> 2;
    const int bS  = b * 2048;
    const int qg0 = qb * 64;

    // Q fragments loaded BEFORE any GLL issue so the loop's vmcnt(8) also
    // implies Q-load completion (FIFO vmcnt: all but the 8 newest are done).
    bf16x8 qf[4];
    {
        const u16* qp = Q + (size_t)(bS + qg0 + wave * 16 + lr) * 4096 + h * 128 + quad * 8;
#pragma unroll
        for (int kc = 0; kc < 4; ++kc) qf[kc] = *(const bf16x8*)(qp + kc * 32);
    }

    f32x4 o[8] = {};
    float mrow[4] = {-1e30f, -1e30f, -1e30f, -1e30f};
    float lrow[4] = {0.f, 0.f, 0.f, 0.f};

    // --- staging source lanes (inverse-swizzled global addresses) ---
    const int ktr = tid >> 4;                       // 0..15
    const int kd  = ((tid & 15) ^ (ktr & 7)) * 8;   // d offset (u16)
    const u16* kg = K + (size_t)(bS + ktr) * 1024 + hk * 128 + kd;
    const int vdr = tid >> 3;                       // 0..31
    const int vk0 = ((tid & 7) ^ (vdr & 7)) * 8;    // key offset (u16)
    const u16* vg = Vt_g + (size_t)(hk * 128 + vdr) * 4096 + bS + vk0;
    u16* kl0 = &Ks[0][0] + wave * 512;              // uniform per-wave base
    u16* vl0 = &Vs[0][0] + wave * 512;

    auto STAGE = [&](int t, int buf) {
        const u16* kgk = kg + (size_t)(t * 64) * 1024;
        const u16* vgk = vg + t * 64;
        u16* klb = kl0 + buf * 8192;
        u16* vlb = vl0 + buf * 8192;
#pragma unroll
        for (int it = 0; it < 4; ++it) {
            GLL16(kgk + (size_t)(it * 16) * 1024, klb + it * 2048);
            GLL16(vgk + (size_t)(it * 32) * 4096, vlb + it * 2048);
        }
    };

    STAGE(0, 0);

    for (int kt = 0; kt <= qb; ++kt) {
        const int cur = kt & 1;
        if (kt < qb) {              // uniform branch
            STAGE(kt + 1, cur ^ 1); // prefetch overlaps this iter's compute
            asm volatile("s_waitcnt vmcnt(8)" ::: "memory");
        } else {
            asm volatile("s_waitcnt vmcnt(0)" ::: "memory");
        }
        __builtin_amdgcn_s_barrier();   // tile kt visible to all waves

        const u16* Ksb = &Ks[cur][0];
        const u16* Vsb = &Vs[cur][0];

        f32x4 sc[4] = {};
        __builtin_amdgcn_s_setprio(1);
#pragma unroll
        for (int t = 0; t < 4; ++t) {
            int key = t * 16 + lr;
#pragma unroll
            for (int kc = 0; kc < 4; ++kc) {
                bf16x8 kf = *(const bf16x8*)(Ksb + key * 128 + (((kc * 4 + quad) ^ (lr & 7)) << 3));
                sc[t] = MFMA16(qf[kc], kf, sc[t]);
            }
        }
        __builtin_amdgcn_s_setprio(0);

        const bool diag = (kt == qb);
#pragma unroll
        for (int t = 0; t < 4; ++t) {
#pragma unroll
            for (int r = 0; r < 4; ++r) {
                float sv = sc[t][r] * scale;
                if (diag) {
                    int key = kt * 64 + t * 16 + lr;
                    int qg  = qg0 + wave * 16 + quad * 4 + r;
                    if (key > qg) sv = -1e30f;
                }
                sc[t][r] = sv;
            }
        }

        float alpha[4];
#pragma unroll
        for (int r = 0; r < 4; ++r) {
            float mx = fmaxf(fmaxf(sc[0][r], sc[1][r]), fmaxf(sc[2][r], sc[3][r]));
#pragma unroll
            for (int d = 1; d < 16; d <<= 1) mx = fmaxf(mx, __shfl_xor(mx, d, 64));
            float mn = fmaxf(mrow[r], mx);
            alpha[r] = __expf(mrow[r] - mn);
            mrow[r]  = mn;
            float rs = 0.f;
#pragma unroll
            for (int t = 0; t < 4; ++t) {
                float e = __expf(sc[t][r] - mn);
                sc[t][r] = e;
                rs += e;
            }
#pragma unroll
            for (int d = 1; d < 16; d <<= 1) rs += __shfl_xor(rs, d, 64);
            lrow[r] = lrow[r] * alpha[r] + rs;
        }
#pragma unroll
        for (int nt = 0; nt < 8; ++nt)
#pragma unroll
            for (int r = 0; r < 4; ++r) o[nt][r] *= alpha[r];

        u16* Pw = Ps + wave * (16 * 72);
#pragma unroll
        for (int t = 0; t < 4; ++t)
#pragma unroll
            for (int r = 0; r < 4; ++r)
                Pw[(quad * 4 + r) * 72 + t * 16 + lr] = f2bf(sc[t][r]);

        bf16x8 pa[2];
#pragma unroll
        for (int c = 0; c < 2; ++c)
            pa[c] = *(const bf16x8*)(Pw + lr * 72 + c * 32 + quad * 8);

        __builtin_amdgcn_s_setprio(1);
#pragma unroll
        for (int nt = 0; nt < 8; ++nt) {
#pragma unroll
            for (int c = 0; c < 2; ++c) {
                bf16x8 bv = *(const bf16x8*)(Vsb + (nt * 16 + lr) * 64 + (((c * 4 + quad) ^ (lr & 7)) << 3));
                o[nt] = MFMA16(pa[c], bv, o[nt]);
            }
        }
        __builtin_amdgcn_s_setprio(0);

        __builtin_amdgcn_s_barrier();   // reads done before next prefetch lands
    }

    float inv[4];
#pragma unroll
    for (int r = 0; r < 4; ++r) inv[r] = 1.0f / lrow[r];
#pragma unroll
    for (int nt = 0; nt < 8; ++nt) {
#pragma unroll
        for (int r = 0; r < 4; ++r) {
            int tok = bS + qg0 + wave * 16 + quad * 4 + r;
            int col = h * 128 + nt * 16 + lr;
            O[(size_t)tok * 4096 + col] = f2bf(o[nt][r] * inv[r]);
        }
    }
}

// ---------------------------------------------------------------------------
extern "C" void kernel_launch(void* const* d_in, const int* in_sizes, int n_in,
                              void* d_out, int out_size, void* d_ws, size_t ws_size,
                              hipStream_t stream) {
    const float* x  = (const float*)d_in[0];
    const float* wq = (const float*)d_in[5];
    const float* wk = (const float*)d_in[6];
    const float* wv = (const float*)d_in[7];
    const float* wo = (const float*)d_in[8];
    float* out = (float*)d_out;

    // Workspace plan (all bf16 scratch):
    //   d_ws[ 0:32MB) qws  : Q projection [4096][4096]; flash O aliases it.
    //   d_ws[32:64MB) wob  : bf16 wo (only if ws_size >= 64MB; else fallback).
    //   d_out (64MB f32, dead until final GEMM writes it):
    //     [ 0:32MB) xb   : bf16 x [4096][4096]
    //     [32:64MB) wqb  : bf16 wq — dead after Q proj, then reused:
    //     [32:40MB) wkb  [40:48MB) wvb  [48:56MB) kws  [56:64MB) vtws
    u16* qws  = (u16*)d_ws;
    u16* xb   = (u16*)d_out;
    u16* wqb  = xb + (32u << 20) / 2;
    u16* wkb  = wqb;
    u16* wvb  = wkb + (8u << 20) / 2;
    u16* kws  = wvb + (8u << 20) / 2;
    u16* vtws = kws + (8u << 20) / 2;   // V^T [1024][4096] bf16

    dim3 blk(256);
    cvt_bf16<<<dim3(2048), blk, 0, stream>>>(x,  xb,  2097152);
    cvt_bf16<<<dim3(2048), blk, 0, stream>>>(wq, wqb, 2097152);
    gemm_bb<false, false><<<dim3(32, 32), blk, 0, stream>>>(xb, wqb, qws, 4096, 4096, 4096);
    cvt_bf16<<<dim3(1024), blk, 0, stream>>>(wk, wkb, 524288);
    cvt_bf16<<<dim3(1024), blk, 0, stream>>>(wv, wvb, 524288);
    gemm_bb<false, false><<<dim3(8, 32), blk, 0, stream>>>(xb, wkb, kws, 4096, 1024, 4096);
    gemm_bb<false, true ><<<dim3(8, 32), blk, 0, stream>>>(xb, wvb, vtws, 4096, 1024, 4096);
    rope_k<<<dim3(40960), blk, 0, stream>>>(qws, kws);
    flash_attn<<<dim3(32, 32, 2), blk, 0, stream>>>(qws, kws, vtws, qws);
    if (ws_size >= (size_t)(64u << 20)) {
        u16* wob = qws + (32u << 20) / 2;
        cvt_bf16<<<dim3(2048), blk, 0, stream>>>(wo, wob, 2097152);
        gemm_bb<true, false><<<dim3(32, 32), blk, 0, stream>>>(qws, wob, out, 4096, 4096, 4096);
    } else {
        gemm_bt<true, true><<<dim3(32, 32), blk, 0, stream>>>(qws, wo, out, 4096, 4096, 4096);
    }
}

// Round 4
// 850.900 us; speedup vs baseline: 2.3622x; 1.2025x over previous
//
#include <hip/hip_runtime.h>
#include <math.h>

typedef unsigned short u16;
typedef short bf16x8 __attribute__((ext_vector_type(8)));
typedef float f32x4 __attribute__((ext_vector_type(4)));
typedef u16 u16x2 __attribute__((ext_vector_type(2)));
typedef u16 u16x4 __attribute__((ext_vector_type(4)));
typedef u16 u16x8 __attribute__((ext_vector_type(8)));

#define MFMA16(a, b, c) __builtin_amdgcn_mfma_f32_16x16x32_bf16(a, b, c, 0, 0, 0)

// direct global->LDS async copy, 16B per lane; dest = wave-uniform base + lane*16
#define GLL16(g, l)                                                  \
    __builtin_amdgcn_global_load_lds(                                \
        (__attribute__((address_space(1))) void*)(g),                \
        (__attribute__((address_space(3))) void*)(l), 16, 0, 0)

__device__ __forceinline__ float bf2f(u16 u) {
    union { unsigned int i; float f; } v;
    v.i = ((unsigned int)u) << 16;
    return v.f;
}
__device__ __forceinline__ u16 f2bf(float f) {
    union { float f; unsigned int i; } v;
    v.f = f;
    unsigned int r = (v.i + 0x7FFFu + ((v.i >> 16) & 1u)) >> 16;
    return (u16)r;
}
__device__ __forceinline__ u16x4 cvt4(f32x4 v) {
    u16x4 r;
#pragma unroll
    for (int j = 0; j < 4; ++j) r[j] = f2bf(v[j]);
    return r;
}

// ---------------------------------------------------------------------------
// Elementwise f32 -> bf16 (RNE), 8 elems/thread/iter, grid-stride.
// ---------------------------------------------------------------------------
__global__ __launch_bounds__(256)
void cvt_bf16(const float* __restrict__ in, u16* __restrict__ out, int n8) {
    int i = blockIdx.x * 256 + threadIdx.x;
    const int stride = gridDim.x * 256;
    for (; i < n8; i += stride) {
        f32x4 a = ((const f32x4*)in)[2 * i];
        f32x4 b = ((const f32x4*)in)[2 * i + 1];
        u16x8 o;
#pragma unroll
        for (int j = 0; j < 4; ++j) { o[j] = f2bf(a[j]); o[4 + j] = f2bf(b[j]); }
        ((u16x8*)out)[i] = o;
    }
}

// ---------------------------------------------------------------------------
// Pure-bf16 GEMM, m97 structure: C[M][N] = A[M][K] @ B[N][K]^T.
// 128x128 tile, BK=32, 4 waves (2x2 of 64x64), mfma_f32_16x16x32_bf16.
// Staging via global_load_lds dwordx4 into linear [128][32] LDS.
// OUT_TRANS: write C transposed as Ct[N][M] (u16x4 per lane, bf16) — used to
// produce V^T for the flash kernel (V needs no RoPE).
// ---------------------------------------------------------------------------
template<bool OUT_F32, bool OUT_TRANS>
__global__ __launch_bounds__(256, 2)
void gemm_bb(const u16* __restrict__ A, const u16* __restrict__ B,
             void* __restrict__ Cv, int M, int N, int K) {
    __shared__ __align__(16) u16 As[128 * 32];
    __shared__ __align__(16) u16 Bs[128 * 32];
    const int tid  = threadIdx.x;
    const int wave = tid >> 6, lane = tid & 63;
    const int lr = lane & 15, quad = lane >> 4;
    const int m0 = blockIdx.y * 128, n0 = blockIdx.x * 128;
    const int wr = (wave >> 1) * 64, wc = (wave & 1) * 64;

    const int srow = tid >> 2;         // 0..63
    const int scol = (tid & 3) * 8;    // 0,8,16,24 (u16 units)
    const u16* ag = A + (size_t)(m0 + srow) * K + scol;
    const u16* bg = B + (size_t)(n0 + srow) * K + scol;
    const size_t rowskip = (size_t)64 * K;
    u16* asl = As + wave * 512;        // per-wave uniform LDS base (u16 units)
    u16* bsl = Bs + wave * 512;

    f32x4 acc[4][4] = {};

    for (int k0 = 0; k0 < K; k0 += 32) {
        __syncthreads();
        GLL16(ag + k0,           asl);
        GLL16(ag + rowskip + k0, asl + 2048);
        GLL16(bg + k0,           bsl);
        GLL16(bg + rowskip + k0, bsl + 2048);
        __syncthreads();

        bf16x8 af[4], bfv[4];
#pragma unroll
        for (int i = 0; i < 4; ++i)
            af[i] = *(const bf16x8*)(As + (wr + i * 16 + lr) * 32 + quad * 8);
#pragma unroll
        for (int j = 0; j < 4; ++j)
            bfv[j] = *(const bf16x8*)(Bs + (wc + j * 16 + lr) * 32 + quad * 8);
#pragma unroll
        for (int i = 0; i < 4; ++i)
#pragma unroll
            for (int j = 0; j < 4; ++j)
                acc[i][j] = MFMA16(af[i], bfv[j], acc[i][j]);
    }

    if (OUT_TRANS) {
#pragma unroll
        for (int i = 0; i < 4; ++i) {
            int row0 = m0 + wr + i * 16 + quad * 4;
#pragma unroll
            for (int j = 0; j < 4; ++j) {
                int col = n0 + wc + j * 16 + lr;
                *(u16x4*)((u16*)Cv + (size_t)col * M + row0) = cvt4(acc[i][j]);
            }
        }
        return;
    }
#pragma unroll
    for (int i = 0; i < 4; ++i) {
#pragma unroll
        for (int r = 0; r < 4; ++r) {
            int row = m0 + wr + i * 16 + quad * 4 + r;
#pragma unroll
            for (int j = 0; j < 4; ++j) {
                int col = n0 + wc + j * 16 + lr;
                if (OUT_F32)
                    ((float*)Cv)[(size_t)row * N + col] = acc[i][j][r];
                else
                    ((u16*)Cv)[(size_t)row * N + col] = f2bf(acc[i][j][r]);
            }
        }
    }
}

// ---------------------------------------------------------------------------
// Legacy mixed GEMM — O-projection fallback when ws_size < 64 MB.
// ---------------------------------------------------------------------------
template<bool A_BF16, bool OUT_F32>
__global__ __launch_bounds__(256, 2)
void gemm_bt(const void* __restrict__ Av, const float* __restrict__ W,
             void* __restrict__ Cv, int M, int N, int K) {
    __shared__ __align__(16) u16 As[128 * 40];
    __shared__ __align__(16) u16 Bs[128 * 40];
    const int tid  = threadIdx.x;
    const int wave = tid >> 6, lane = tid & 63;
    const int lr = lane & 15, quad = lane >> 4;
    const int m0 = blockIdx.y * 128, n0 = blockIdx.x * 128;
    const int wr = (wave >> 1) * 64, wc = (wave & 1) * 64;

    const int r8 = tid >> 3;
    const int c4 = (tid & 7) * 4;
    const int r4 = tid >> 2;
    const int c8 = (tid & 3) * 8;

    f32x4 acc[4][4] = {};

    for (int k0 = 0; k0 < K; k0 += 32) {
        f32x4 wreg[4];
#pragma unroll
        for (int rep = 0; rep < 4; ++rep)
            wreg[rep] = *(const f32x4*)(W + (size_t)(n0 + rep * 32 + r8) * K + k0 + c4);
        f32x4 aregf[4];
        u16x8 aregb[2];
        if (A_BF16) {
#pragma unroll
            for (int rep = 0; rep < 2; ++rep)
                aregb[rep] = *(const u16x8*)((const u16*)Av + (size_t)(m0 + rep * 64 + r4) * K + k0 + c8);
        } else {
#pragma unroll
            for (int rep = 0; rep < 4; ++rep)
                aregf[rep] = *(const f32x4*)((const float*)Av + (size_t)(m0 + rep * 32 + r8) * K + k0 + c4);
        }
        __syncthreads();
#pragma unroll
        for (int rep = 0; rep < 4; ++rep)
            *(u16x4*)(Bs + (rep * 32 + r8) * 40 + c4) = cvt4(wreg[rep]);
        if (A_BF16) {
#pragma unroll
            for (int rep = 0; rep < 2; ++rep)
                *(u16x8*)(As + (rep * 64 + r4) * 40 + c8) = aregb[rep];
        } else {
#pragma unroll
            for (int rep = 0; rep < 4; ++rep)
                *(u16x4*)(As + (rep * 32 + r8) * 40 + c4) = cvt4(aregf[rep]);
        }
        __syncthreads();

        bf16x8 af[4], bfv[4];
#pragma unroll
        for (int i = 0; i < 4; ++i)
            af[i] = *(const bf16x8*)(As + (wr + i * 16 + lr) * 40 + quad * 8);
#pragma unroll
        for (int j = 0; j < 4; ++j)
            bfv[j] = *(const bf16x8*)(Bs + (wc + j * 16 + lr) * 40 + quad * 8);
#pragma unroll
        for (int i = 0; i < 4; ++i)
#pragma unroll
            for (int j = 0; j < 4; ++j)
                acc[i][j] = MFMA16(af[i], bfv[j], acc[i][j]);
    }

#pragma unroll
    for (int i = 0; i < 4; ++i) {
#pragma unroll
        for (int r = 0; r < 4; ++r) {
            int row = m0 + wr + i * 16 + quad * 4 + r;
#pragma unroll
            for (int j = 0; j < 4; ++j) {
                int col = n0 + wc + j * 16 + lr;
                if (OUT_F32)
                    ((float*)Cv)[(size_t)row * N + col] = acc[i][j][r];
                else
                    ((u16*)Cv)[(size_t)row * N + col] = f2bf(acc[i][j][r]);
            }
        }
    }
}

// ---------------------------------------------------------------------------
// RoPE in-place on bf16 q [4096][32*128] and k [4096][8*128] (V untouched).
// ---------------------------------------------------------------------------
__global__ void rope_k(u16* __restrict__ q, u16* __restrict__ kk) {
    const int QP = 2 * 2048 * 32 * 64;  // 8388608
    const int KP = 2 * 2048 * 8 * 64;   // 2097152
    int idx = blockIdx.x * 256 + threadIdx.x;
    u16* ptr;
    int s, i;
    if (idx < QP) {
        i = idx & 63;
        int h = (idx >> 6) & 31;
        int m = idx >> 11;
        s = m & 2047;
        ptr = q + (size_t)m * 4096 + h * 128 + 2 * i;
    } else {
        idx -= QP;
        if (idx >= KP) return;
        i = idx & 63;
        int h = (idx >> 6) & 7;
        int m = idx >> 9;
        s = m & 2047;
        ptr = kk + (size_t)m * 1024 + h * 128 + 2 * i;
    }
    float inv = expf(-9.210340371976184f * (float)(2 * i) * (1.0f / 128.0f));
    float ang = (float)s * inv;
    float sn = sinf(ang);
    float c  = cosf(ang);
    u16x2 v = *(u16x2*)ptr;
    float tr = bf2f(v[0]), ti = bf2f(v[1]);
    u16x2 o;
    o[0] = f2bf(tr * c - ti * sn);
    o[1] = f2bf(tr * sn + ti * c);
    *(u16x2*)ptr = o;
}

// ---------------------------------------------------------------------------
// Flash attention, causal, GQA rep=4, bf16 in/out. grid (S/128, H, B).
// Block x-index p processes q-tiles (31-p) then (p) sequentially — each block
// does exactly 33 KV-tile iterations (perfect causal load balance).
// Softmax latency fixes vs prior rev:
//  - row-SUM comes from 2 extra MFMAs against an all-ones B fragment (rsacc
//    accumulates in the same reg layout as o) — the 4-step sum shfl chain and
//    lrow bookkeeping are gone.
//  - defer-max (THR=8): the 4-step max shfl chain + o/rsacc rescale run only
//    when __all(lane pmax - mrow <= 8) fails (always on the first tile since
//    mrow=-1e30, rare after). Steady-state iters have NO cross-lane ops.
// K/V staging: double-buffered LDS via global_load_lds, tile kt+1 prefetched
// at top of iter kt, counted s_waitcnt vmcnt(8) (never 0 mid-loop), raw
// s_barrier. 16B-chunk XOR swizzle (chunk ^= row&7): linear LDS dest +
// inverse-swizzled GLOBAL source, read back with same XOR.
// ---------------------------------------------------------------------------
__global__ __launch_bounds__(256, 2)
void flash_attn(const u16* Q, const u16* __restrict__ K,
                const u16* __restrict__ Vt_g, u16* O) {
    __shared__ __align__(16) u16 Ks[2][64 * 128];   // swizzled 256B rows
    __shared__ __align__(16) u16 Vs[2][128 * 64];   // V^T, swizzled 128B rows
    __shared__ __align__(16) u16 Ps[4 * 16 * 72];
    const float scale = 0.08838834764831845f;  // 128^-0.5
    const int tid  = threadIdx.x;
    const int wave = tid >> 6, lane = tid & 63;
    const int lr = lane & 15, quad = lane >> 4;
    const int p = blockIdx.x;                  // 0..15 (pair index)
    const int h = blockIdx.y, b = blockIdx.z;
    const int hk  = h >> 2;
    const int bS  = b * 2048;

    // --- staging source lanes (inverse-swizzled global addresses) ---
    const int ktr = tid >> 4;                       // 0..15
    const int kd  = ((tid & 15) ^ (ktr & 7)) * 8;   // d offset (u16)
    const u16* kg = K + (size_t)(bS + ktr) * 1024 + hk * 128 + kd;
    const int vdr = tid >> 3;                       // 0..31
    const int vk0 = ((tid & 7) ^ (vdr & 7)) * 8;    // key offset (u16)
    const u16* vg = Vt_g + (size_t)(hk * 128 + vdr) * 4096 + bS + vk0;
    u16* kl0 = &Ks[0][0] + wave * 512;              // uniform per-wave base
    u16* vl0 = &Vs[0][0] + wave * 512;

    auto STAGE = [&](int t, int buf) {
        const u16* kgk = kg + (size_t)(t * 64) * 1024;
        const u16* vgk = vg + t * 64;
        u16* klb = kl0 + buf * 8192;
        u16* vlb = vl0 + buf * 8192;
#pragma unroll
        for (int it = 0; it < 4; ++it) {
            GLL16(kgk + (size_t)(it * 16) * 1024, klb + it * 2048);
            GLL16(vgk + (size_t)(it * 32) * 4096, vlb + it * 2048);
        }
    };

    bf16x8 onesf;
#pragma unroll
    for (int j = 0; j < 8; ++j) onesf[j] = (short)0x3F80;  // bf16 1.0

    for (int pass = 0; pass < 2; ++pass) {
        const int qb  = pass ? p : 31 - p;
        const int qg0 = qb * 64;

        // Q fragments loaded BEFORE the pass's GLL issues so the loop's
        // vmcnt(8) also implies Q-load completion (FIFO vmcnt).
        bf16x8 qf[4];
        {
            const u16* qp = Q + (size_t)(bS + qg0 + wave * 16 + lr) * 4096 + h * 128 + quad * 8;
#pragma unroll
            for (int kc = 0; kc < 4; ++kc) qf[kc] = *(const bf16x8*)(qp + kc * 32);
        }

        f32x4 o[8] = {};
        f32x4 rsacc = {};
        float mrow[4] = {-1e30f, -1e30f, -1e30f, -1e30f};

        STAGE(0, 0);

        for (int kt = 0; kt <= qb; ++kt) {
            const int cur = kt & 1;
            if (kt < qb) {              // uniform branch
                STAGE(kt + 1, cur ^ 1); // prefetch overlaps this iter's compute
                asm volatile("s_waitcnt vmcnt(8)" ::: "memory");
            } else {
                asm volatile("s_waitcnt vmcnt(0)" ::: "memory");
            }
            __builtin_amdgcn_s_barrier();   // tile kt visible to all waves

            const u16* Ksb = &Ks[cur][0];
            const u16* Vsb = &Vs[cur][0];

            f32x4 sc[4] = {};
            __builtin_amdgcn_s_setprio(1);
#pragma unroll
            for (int t = 0; t < 4; ++t) {
                int key = t * 16 + lr;
#pragma unroll
                for (int kc = 0; kc < 4; ++kc) {
                    bf16x8 kf = *(const bf16x8*)(Ksb + key * 128 + (((kc * 4 + quad) ^ (lr & 7)) << 3));
                    sc[t] = MFMA16(qf[kc], kf, sc[t]);
                }
            }
            __builtin_amdgcn_s_setprio(0);

            const bool diag = (kt == qb);
#pragma unroll
            for (int t = 0; t < 4; ++t) {
#pragma unroll
                for (int r = 0; r < 4; ++r) {
                    float sv = sc[t][r] * scale;
                    if (diag) {
                        int key = kt * 64 + t * 16 + lr;
                        int qg  = qg0 + wave * 16 + quad * 4 + r;
                        if (key > qg) sv = -1e30f;
                    }
                    sc[t][r] = sv;
                }
            }

            // lane-local partial max per row (keys t*16+lr of row quad*4+r)
            float pmax[4];
#pragma unroll
            for (int r = 0; r < 4; ++r)
                pmax[r] = fmaxf(fmaxf(sc[0][r], sc[1][r]), fmaxf(sc[2][r], sc[3][r]));
            bool ok = true;
#pragma unroll
            for (int r = 0; r < 4; ++r) ok = ok && (pmax[r] - mrow[r] <= 8.0f);
            if (!__all(ok)) {
                // exact path: cross-lane row max + rescale accumulators
                float alpha[4];
#pragma unroll
                for (int r = 0; r < 4; ++r) {
                    float mx = pmax[r];
#pragma unroll
                    for (int d = 1; d < 16; d <<= 1) mx = fmaxf(mx, __shfl_xor(mx, d, 64));
                    float mn = fmaxf(mrow[r], mx);
                    alpha[r] = __expf(mrow[r] - mn);
                    mrow[r]  = mn;
                }
#pragma unroll
                for (int nt = 0; nt < 8; ++nt)
#pragma unroll
                    for (int r = 0; r < 4; ++r) o[nt][r] *= alpha[r];
#pragma unroll
                for (int r = 0; r < 4; ++r) rsacc[r] *= alpha[r];
            }
#pragma unroll
            for (int t = 0; t < 4; ++t)
#pragma unroll
                for (int r = 0; r < 4; ++r)
                    sc[t][r] = __expf(sc[t][r] - mrow[r]);

            u16* Pw = Ps + wave * (16 * 72);
#pragma unroll
            for (int t = 0; t < 4; ++t)
#pragma unroll
                for (int r = 0; r < 4; ++r)
                    Pw[(quad * 4 + r) * 72 + t * 16 + lr] = f2bf(sc[t][r]);

            bf16x8 pa[2];
#pragma unroll
            for (int c = 0; c < 2; ++c)
                pa[c] = *(const bf16x8*)(Pw + lr * 72 + c * 32 + quad * 8);

            __builtin_amdgcn_s_setprio(1);
            // row-sum via ones-MFMA: rsacc reg r = sum_k P[quad*4+r][k]
            rsacc = MFMA16(pa[0], onesf, rsacc);
            rsacc = MFMA16(pa[1], onesf, rsacc);
#pragma unroll
            for (int nt = 0; nt < 8; ++nt) {
#pragma unroll
                for (int c = 0; c < 2; ++c) {
                    bf16x8 bv = *(const bf16x8*)(Vsb + (nt * 16 + lr) * 64 + (((c * 4 + quad) ^ (lr & 7)) << 3));
                    o[nt] = MFMA16(pa[c], bv, o[nt]);
                }
            }
            __builtin_amdgcn_s_setprio(0);

            __builtin_amdgcn_s_barrier();   // reads done before next prefetch lands
        }

        float inv[4];
#pragma unroll
        for (int r = 0; r < 4; ++r) inv[r] = 1.0f / rsacc[r];
#pragma unroll
        for (int nt = 0; nt < 8; ++nt) {
#pragma unroll
            for (int r = 0; r < 4; ++r) {
                int tok = bS + qg0 + wave * 16 + quad * 4 + r;
                int col = h * 128 + nt * 16 + lr;
                O[(size_t)tok * 4096 + col] = f2bf(o[nt][r] * inv[r]);
            }
        }
    }
}

// ---------------------------------------------------------------------------
extern "C" void kernel_launch(void* const* d_in, const int* in_sizes, int n_in,
                              void* d_out, int out_size, void* d_ws, size_t ws_size,
                              hipStream_t stream) {
    const float* x  = (const float*)d_in[0];
    const float* wq = (const float*)d_in[5];
    const float* wk = (const float*)d_in[6];
    const float* wv = (const float*)d_in[7];
    const float* wo = (const float*)d_in[8];
    float* out = (float*)d_out;

    // Workspace plan (all bf16 scratch):
    //   d_ws[ 0:32MB) qws  : Q projection [4096][4096]; flash O aliases it.
    //   d_ws[32:64MB) wob  : bf16 wo (only if ws_size >= 64MB; else fallback).
    //   d_out (64MB f32, dead until final GEMM writes it):
    //     [ 0:32MB) xb   : bf16 x [4096][4096]
    //     [32:64MB) wqb  : bf16 wq — dead after Q proj, then reused:
    //     [32:40MB) wkb  [40:48MB) wvb  [48:56MB) kws  [56:64MB) vtws
    u16* qws  = (u16*)d_ws;
    u16* xb   = (u16*)d_out;
    u16* wqb  = xb + (32u << 20) / 2;
    u16* wkb  = wqb;
    u16* wvb  = wkb + (8u << 20) / 2;
    u16* kws  = wvb + (8u << 20) / 2;
    u16* vtws = kws + (8u << 20) / 2;   // V^T [1024][4096] bf16

    dim3 blk(256);
    cvt_bf16<<<dim3(2048), blk, 0, stream>>>(x,  xb,  2097152);
    cvt_bf16<<<dim3(2048), blk, 0, stream>>>(wq, wqb, 2097152);
    gemm_bb<false, false><<<dim3(32, 32), blk, 0, stream>>>(xb, wqb, qws, 4096, 4096, 4096);
    cvt_bf16<<<dim3(1024), blk, 0, stream>>>(wk, wkb, 524288);
    cvt_bf16<<<dim3(1024), blk, 0, stream>>>(wv, wvb, 524288);
    gemm_bb<false, false><<<dim3(8, 32), blk, 0, stream>>>(xb, wkb, kws, 4096, 1024, 4096);
    gemm_bb<false, true ><<<dim3(8, 32), blk, 0, stream>>>(xb, wvb, vtws, 4096, 1024, 4096);
    rope_k<<<dim3(40960), blk, 0, stream>>>(qws, kws);
    flash_attn<<<dim3(16, 32, 2), blk, 0, stream>>>(qws, kws, vtws, qws);
    if (ws_size >= (size_t)(64u << 20)) {
        u16* wob = qws + (32u << 20) / 2;
        cvt_bf16<<<dim3(2048), blk, 0, stream>>>(wo, wob, 2097152);
        gemm_bb<true, false><<<dim3(32, 32), blk, 0, stream>>>(qws, wob, out, 4096, 4096, 4096);
    } else {
        gemm_bt<true, true><<<dim3(32, 32), blk, 0, stream>>>(qws, wo, out, 4096, 4096, 4096);
    }
}

// Round 5
// 753.841 us; speedup vs baseline: 2.6663x; 1.1288x over previous
//
#include <hip/hip_runtime.h>
#include <math.h>

typedef unsigned short u16;
typedef short bf16x8 __attribute__((ext_vector_type(8)));
typedef float f32x4 __attribute__((ext_vector_type(4)));
typedef u16 u16x2 __attribute__((ext_vector_type(2)));
typedef u16 u16x4 __attribute__((ext_vector_type(4)));
typedef u16 u16x8 __attribute__((ext_vector_type(8)));

#define MFMA16(a, b, c) __builtin_amdgcn_mfma_f32_16x16x32_bf16(a, b, c, 0, 0, 0)

// direct global->LDS async copy, 16B per lane; dest = wave-uniform base + lane*16
#define GLL16(g, l)                                                  \
    __builtin_amdgcn_global_load_lds(                                \
        (__attribute__((address_space(1))) void*)(g),                \
        (__attribute__((address_space(3))) void*)(l), 16, 0, 0)

__device__ __forceinline__ float bf2f(u16 u) {
    union { unsigned int i; float f; } v;
    v.i = ((unsigned int)u) << 16;
    return v.f;
}
__device__ __forceinline__ u16 f2bf(float f) {
    union { float f; unsigned int i; } v;
    v.f = f;
    unsigned int r = (v.i + 0x7FFFu + ((v.i >> 16) & 1u)) >> 16;
    return (u16)r;
}
__device__ __forceinline__ u16x4 cvt4(f32x4 v) {
    u16x4 r;
#pragma unroll
    for (int j = 0; j < 4; ++j) r[j] = f2bf(v[j]);
    return r;
}

// ---------------------------------------------------------------------------
// Elementwise f32 -> bf16 (RNE), 8 elems/thread/iter, grid-stride.
// ---------------------------------------------------------------------------
__global__ __launch_bounds__(256)
void cvt_bf16(const float* __restrict__ in, u16* __restrict__ out, int n8) {
    int i = blockIdx.x * 256 + threadIdx.x;
    const int stride = gridDim.x * 256;
    for (; i < n8; i += stride) {
        f32x4 a = ((const f32x4*)in)[2 * i];
        f32x4 b = ((const f32x4*)in)[2 * i + 1];
        u16x8 o;
#pragma unroll
        for (int j = 0; j < 4; ++j) { o[j] = f2bf(a[j]); o[4 + j] = f2bf(b[j]); }
        ((u16x8*)out)[i] = o;
    }
}

// ---------------------------------------------------------------------------
// Pure-bf16 GEMM, m97 structure: C = A[M][K] @ B[N][K]^T.
// 128x128 tile, BK=32, 4 waves (2x2 of 64x64), mfma_f32_16x16x32_bf16.
// Staging via global_load_lds dwordx4 into linear [128][32] LDS.
// Epilogue MODE:
//   1 = f32 C [M][N]                      (O projection)
//   2 = bf16 C [M][N] with fused RoPE     (Q projection; fc/fs tables)
//   3 = split: col<1024 -> bf16 roped K [M][1024]; col>=1024 -> transposed
//       bf16 V^T store Ct[(col-1024)][M]  (merged K+V projection, N=2048)
// RoPE pair exchange: adjacent cols live in adjacent lanes -> __shfl_xor(v,1).
// Branch on col>=1024 is wave-uniform (16-col spans never cross 1024).
// ---------------------------------------------------------------------------
template<int MODE>
__global__ __launch_bounds__(256, 2)
void gemm_bb(const u16* __restrict__ A, const u16* __restrict__ B,
             void* __restrict__ Cv, u16* __restrict__ Ct,
             const float* __restrict__ fc, const float* __restrict__ fs,
             int M, int N, int K) {
    __shared__ __align__(16) u16 As[128 * 32];
    __shared__ __align__(16) u16 Bs[128 * 32];
    const int tid  = threadIdx.x;
    const int wave = tid >> 6, lane = tid & 63;
    const int lr = lane & 15, quad = lane >> 4;
    const int m0 = blockIdx.y * 128, n0 = blockIdx.x * 128;
    const int wr = (wave >> 1) * 64, wc = (wave & 1) * 64;

    const int srow = tid >> 2;         // 0..63
    const int scol = (tid & 3) * 8;    // 0,8,16,24 (u16 units)
    const u16* ag = A + (size_t)(m0 + srow) * K + scol;
    const u16* bg = B + (size_t)(n0 + srow) * K + scol;
    const size_t rowskip = (size_t)64 * K;
    u16* asl = As + wave * 512;        // per-wave uniform LDS base (u16 units)
    u16* bsl = Bs + wave * 512;

    f32x4 acc[4][4] = {};

    for (int k0 = 0; k0 < K; k0 += 32) {
        __syncthreads();
        GLL16(ag + k0,           asl);
        GLL16(ag + rowskip + k0, asl + 2048);
        GLL16(bg + k0,           bsl);
        GLL16(bg + rowskip + k0, bsl + 2048);
        __syncthreads();

        bf16x8 af[4], bfv[4];
#pragma unroll
        for (int i = 0; i < 4; ++i)
            af[i] = *(const bf16x8*)(As + (wr + i * 16 + lr) * 32 + quad * 8);
#pragma unroll
        for (int j = 0; j < 4; ++j)
            bfv[j] = *(const bf16x8*)(Bs + (wc + j * 16 + lr) * 32 + quad * 8);
#pragma unroll
        for (int i = 0; i < 4; ++i)
#pragma unroll
            for (int j = 0; j < 4; ++j)
                acc[i][j] = MFMA16(af[i], bfv[j], acc[i][j]);
    }

    // epilogue: C/D layout col=lane&15, row=quad*4+reg
#pragma unroll
    for (int i = 0; i < 4; ++i) {
        const int row0 = m0 + wr + i * 16 + quad * 4;
#pragma unroll
        for (int j = 0; j < 4; ++j) {
            const int col = n0 + wc + j * 16 + lr;
            if (MODE == 1) {
#pragma unroll
                for (int r = 0; r < 4; ++r)
                    ((float*)Cv)[(size_t)(row0 + r) * N + col] = acc[i][j][r];
            } else if (MODE == 3 && col >= 1024) {
                *(u16x4*)(Ct + (size_t)(col - 1024) * M + row0) = cvt4(acc[i][j]);
            } else {
                // fused RoPE (tables are the exact reference cos/sin)
                const int   ifq = (col >> 1) & 63;
                const float sgn = (col & 1) ? 1.0f : -1.0f;
                const int   ld  = (MODE == 3) ? 1024 : 4096;
#pragma unroll
                for (int r = 0; r < 4; ++r) {
                    int tok = (row0 + r) & 2047;
                    float c = fc[tok * 64 + ifq];
                    float s = fs[tok * 64 + ifq];
                    float v  = acc[i][j][r];
                    float pv = __shfl_xor(v, 1, 64);
                    ((u16*)Cv)[(size_t)(row0 + r) * ld + col] = f2bf(v * c + sgn * (pv * s));
                }
            }
        }
    }
}

// ---------------------------------------------------------------------------
// Legacy mixed GEMM — O-projection fallback when ws_size < 64 MB.
// ---------------------------------------------------------------------------
template<bool A_BF16, bool OUT_F32>
__global__ __launch_bounds__(256, 2)
void gemm_bt(const void* __restrict__ Av, const float* __restrict__ W,
             void* __restrict__ Cv, int M, int N, int K) {
    __shared__ __align__(16) u16 As[128 * 40];
    __shared__ __align__(16) u16 Bs[128 * 40];
    const int tid  = threadIdx.x;
    const int wave = tid >> 6, lane = tid & 63;
    const int lr = lane & 15, quad = lane >> 4;
    const int m0 = blockIdx.y * 128, n0 = blockIdx.x * 128;
    const int wr = (wave >> 1) * 64, wc = (wave & 1) * 64;

    const int r8 = tid >> 3;
    const int c4 = (tid & 7) * 4;
    const int r4 = tid >> 2;
    const int c8 = (tid & 3) * 8;

    f32x4 acc[4][4] = {};

    for (int k0 = 0; k0 < K; k0 += 32) {
        f32x4 wreg[4];
#pragma unroll
        for (int rep = 0; rep < 4; ++rep)
            wreg[rep] = *(const f32x4*)(W + (size_t)(n0 + rep * 32 + r8) * K + k0 + c4);
        f32x4 aregf[4];
        u16x8 aregb[2];
        if (A_BF16) {
#pragma unroll
            for (int rep = 0; rep < 2; ++rep)
                aregb[rep] = *(const u16x8*)((const u16*)Av + (size_t)(m0 + rep * 64 + r4) * K + k0 + c8);
        } else {
#pragma unroll
            for (int rep = 0; rep < 4; ++rep)
                aregf[rep] = *(const f32x4*)((const float*)Av + (size_t)(m0 + rep * 32 + r8) * K + k0 + c4);
        }
        __syncthreads();
#pragma unroll
        for (int rep = 0; rep < 4; ++rep)
            *(u16x4*)(Bs + (rep * 32 + r8) * 40 + c4) = cvt4(wreg[rep]);
        if (A_BF16) {
#pragma unroll
            for (int rep = 0; rep < 2; ++rep)
                *(u16x8*)(As + (rep * 64 + r4) * 40 + c8) = aregb[rep];
        } else {
#pragma unroll
            for (int rep = 0; rep < 4; ++rep)
                *(u16x4*)(As + (rep * 32 + r8) * 40 + c4) = cvt4(aregf[rep]);
        }
        __syncthreads();

        bf16x8 af[4], bfv[4];
#pragma unroll
        for (int i = 0; i < 4; ++i)
            af[i] = *(const bf16x8*)(As + (wr + i * 16 + lr) * 40 + quad * 8);
#pragma unroll
        for (int j = 0; j < 4; ++j)
            bfv[j] = *(const bf16x8*)(Bs + (wc + j * 16 + lr) * 40 + quad * 8);
#pragma unroll
        for (int i = 0; i < 4; ++i)
#pragma unroll
            for (int j = 0; j < 4; ++j)
                acc[i][j] = MFMA16(af[i], bfv[j], acc[i][j]);
    }

#pragma unroll
    for (int i = 0; i < 4; ++i) {
#pragma unroll
        for (int r = 0; r < 4; ++r) {
            int row = m0 + wr + i * 16 + quad * 4 + r;
#pragma unroll
            for (int j = 0; j < 4; ++j) {
                int col = n0 + wc + j * 16 + lr;
                if (OUT_F32)
                    ((float*)Cv)[(size_t)row * N + col] = acc[i][j][r];
                else
                    ((u16*)Cv)[(size_t)row * N + col] = f2bf(acc[i][j][r]);
            }
        }
    }
}

// ---------------------------------------------------------------------------
// Flash attention, causal, GQA rep=4, bf16 in/out. grid (S/128, H, B).
// Block x-index p processes q-tiles (31-p) then (p) — 33 KV-tiles per block
// (perfect causal balance). Row-sum via ones-MFMA; defer-max (THR=8) so
// steady-state iterations have no cross-lane ops. Double-buffered K/V LDS
// via global_load_lds, counted s_waitcnt vmcnt(8), raw s_barrier, 16B-chunk
// XOR swizzle (linear LDS dest + inverse-swizzled global source).
// ---------------------------------------------------------------------------
__global__ __launch_bounds__(256, 2)
void flash_attn(const u16* Q, const u16* __restrict__ K,
                const u16* __restrict__ Vt_g, u16* O) {
    __shared__ __align__(16) u16 Ks[2][64 * 128];   // swizzled 256B rows
    __shared__ __align__(16) u16 Vs[2][128 * 64];   // V^T, swizzled 128B rows
    __shared__ __align__(16) u16 Ps[4 * 16 * 72];
    const float scale = 0.08838834764831845f;  // 128^-0.5
    const int tid  = threadIdx.x;
    const int wave = tid >> 6, lane = tid & 63;
    const int lr = lane & 15, quad = lane >> 4;
    const int p = blockIdx.x;                  // 0..15 (pair index)
    const int h = blockIdx.y, b = blockIdx.z;
    const int hk  = h >> 2;
    const int bS  = b * 2048;

    const int ktr = tid >> 4;                       // 0..15
    const int kd  = ((tid & 15) ^ (ktr & 7)) * 8;   // d offset (u16)
    const u16* kg = K + (size_t)(bS + ktr) * 1024 + hk * 128 + kd;
    const int vdr = tid >> 3;                       // 0..31
    const int vk0 = ((tid & 7) ^ (vdr & 7)) * 8;    // key offset (u16)
    const u16* vg = Vt_g + (size_t)(hk * 128 + vdr) * 4096 + bS + vk0;
    u16* kl0 = &Ks[0][0] + wave * 512;              // uniform per-wave base
    u16* vl0 = &Vs[0][0] + wave * 512;

    auto STAGE = [&](int t, int buf) {
        const u16* kgk = kg + (size_t)(t * 64) * 1024;
        const u16* vgk = vg + t * 64;
        u16* klb = kl0 + buf * 8192;
        u16* vlb = vl0 + buf * 8192;
#pragma unroll
        for (int it = 0; it < 4; ++it) {
            GLL16(kgk + (size_t)(it * 16) * 1024, klb + it * 2048);
            GLL16(vgk + (size_t)(it * 32) * 4096, vlb + it * 2048);
        }
    };

    bf16x8 onesf;
#pragma unroll
    for (int j = 0; j < 8; ++j) onesf[j] = (short)0x3F80;  // bf16 1.0

    for (int pass = 0; pass < 2; ++pass) {
        const int qb  = pass ? p : 31 - p;
        const int qg0 = qb * 64;

        bf16x8 qf[4];
        {
            const u16* qp = Q + (size_t)(bS + qg0 + wave * 16 + lr) * 4096 + h * 128 + quad * 8;
#pragma unroll
            for (int kc = 0; kc < 4; ++kc) qf[kc] = *(const bf16x8*)(qp + kc * 32);
        }

        f32x4 o[8] = {};
        f32x4 rsacc = {};
        float mrow[4] = {-1e30f, -1e30f, -1e30f, -1e30f};

        STAGE(0, 0);

        for (int kt = 0; kt <= qb; ++kt) {
            const int cur = kt & 1;
            if (kt < qb) {              // uniform branch
                STAGE(kt + 1, cur ^ 1); // prefetch overlaps this iter's compute
                asm volatile("s_waitcnt vmcnt(8)" ::: "memory");
            } else {
                asm volatile("s_waitcnt vmcnt(0)" ::: "memory");
            }
            __builtin_amdgcn_s_barrier();   // tile kt visible to all waves

            const u16* Ksb = &Ks[cur][0];
            const u16* Vsb = &Vs[cur][0];

            f32x4 sc[4] = {};
            __builtin_amdgcn_s_setprio(1);
#pragma unroll
            for (int t = 0; t < 4; ++t) {
                int key = t * 16 + lr;
#pragma unroll
                for (int kc = 0; kc < 4; ++kc) {
                    bf16x8 kf = *(const bf16x8*)(Ksb + key * 128 + (((kc * 4 + quad) ^ (lr & 7)) << 3));
                    sc[t] = MFMA16(qf[kc], kf, sc[t]);
                }
            }
            __builtin_amdgcn_s_setprio(0);

            const bool diag = (kt == qb);
#pragma unroll
            for (int t = 0; t < 4; ++t) {
#pragma unroll
                for (int r = 0; r < 4; ++r) {
                    float sv = sc[t][r] * scale;
                    if (diag) {
                        int key = kt * 64 + t * 16 + lr;
                        int qg  = qg0 + wave * 16 + quad * 4 + r;
                        if (key > qg) sv = -1e30f;
                    }
                    sc[t][r] = sv;
                }
            }

            float pmax[4];
#pragma unroll
            for (int r = 0; r < 4; ++r)
                pmax[r] = fmaxf(fmaxf(sc[0][r], sc[1][r]), fmaxf(sc[2][r], sc[3][r]));
            bool ok = true;
#pragma unroll
            for (int r = 0; r < 4; ++r) ok = ok && (pmax[r] - mrow[r] <= 8.0f);
            if (!__all(ok)) {
                float alpha[4];
#pragma unroll
                for (int r = 0; r < 4; ++r) {
                    float mx = pmax[r];
#pragma unroll
                    for (int d = 1; d < 16; d <<= 1) mx = fmaxf(mx, __shfl_xor(mx, d, 64));
                    float mn = fmaxf(mrow[r], mx);
                    alpha[r] = __expf(mrow[r] - mn);
                    mrow[r]  = mn;
                }
#pragma unroll
                for (int nt = 0; nt < 8; ++nt)
#pragma unroll
                    for (int r = 0; r < 4; ++r) o[nt][r] *= alpha[r];
#pragma unroll
                for (int r = 0; r < 4; ++r) rsacc[r] *= alpha[r];
            }
#pragma unroll
            for (int t = 0; t < 4; ++t)
#pragma unroll
                for (int r = 0; r < 4; ++r)
                    sc[t][r] = __expf(sc[t][r] - mrow[r]);

            u16* Pw = Ps + wave * (16 * 72);
#pragma unroll
            for (int t = 0; t < 4; ++t)
#pragma unroll
                for (int r = 0; r < 4; ++r)
                    Pw[(quad * 4 + r) * 72 + t * 16 + lr] = f2bf(sc[t][r]);

            bf16x8 pa[2];
#pragma unroll
            for (int c = 0; c < 2; ++c)
                pa[c] = *(const bf16x8*)(Pw + lr * 72 + c * 32 + quad * 8);

            __builtin_amdgcn_s_setprio(1);
            rsacc = MFMA16(pa[0], onesf, rsacc);
            rsacc = MFMA16(pa[1], onesf, rsacc);
#pragma unroll
            for (int nt = 0; nt < 8; ++nt) {
#pragma unroll
                for (int c = 0; c < 2; ++c) {
                    bf16x8 bv = *(const bf16x8*)(Vsb + (nt * 16 + lr) * 64 + (((c * 4 + quad) ^ (lr & 7)) << 3));
                    o[nt] = MFMA16(pa[c], bv, o[nt]);
                }
            }
            __builtin_amdgcn_s_setprio(0);

            __builtin_amdgcn_s_barrier();   // reads done before next prefetch lands
        }

        float inv[4];
#pragma unroll
        for (int r = 0; r < 4; ++r) inv[r] = 1.0f / rsacc[r];
#pragma unroll
        for (int nt = 0; nt < 8; ++nt) {
#pragma unroll
            for (int r = 0; r < 4; ++r) {
                int tok = bS + qg0 + wave * 16 + quad * 4 + r;
                int col = h * 128 + nt * 16 + lr;
                O[(size_t)tok * 4096 + col] = f2bf(o[nt][r] * inv[r]);
            }
        }
    }
}

// ---------------------------------------------------------------------------
extern "C" void kernel_launch(void* const* d_in, const int* in_sizes, int n_in,
                              void* d_out, int out_size, void* d_ws, size_t ws_size,
                              hipStream_t stream) {
    const float* x  = (const float*)d_in[0];
    const float* fc = (const float*)d_in[1];   // freqs_cos [2048][64] f32
    const float* fs = (const float*)d_in[2];   // freqs_sin [2048][64] f32
    const float* wq = (const float*)d_in[5];
    const float* wk = (const float*)d_in[6];
    const float* wv = (const float*)d_in[7];
    const float* wo = (const float*)d_in[8];
    float* out = (float*)d_out;

    // Workspace plan (bf16 scratch; 1 MB = 524288 u16):
    //   d_ws[ 0:32MB) qws : Q projection (roped in-epilogue); flash O aliases.
    //   d_ws[32:64MB) wob : bf16 wo (free until used; requires ws >= 64MB).
    //   d_out (64MB f32, dead until final GEMM writes it):
    //     [ 0:32MB) xb  : bf16 x
    //     [32:64MB) wqb : bf16 wq — dead after Q proj, then reused:
    //       [32:40MB) kws (roped K, [4096][1024])
    //       [40:48MB) vtws (V^T, [1024][4096])
    //       [48:64MB) wkvb (bf16 wk‖wv, [2048][4096], contiguous)
    u16* qws  = (u16*)d_ws;
    u16* xb   = (u16*)d_out;
    u16* wqb  = xb + (size_t)32 * 524288;
    u16* kws  = xb + (size_t)32 * 524288;
    u16* vtws = xb + (size_t)40 * 524288;
    u16* wkvb = xb + (size_t)48 * 524288;

    dim3 blk(256);
    cvt_bf16<<<dim3(2048), blk, 0, stream>>>(x,  xb,  2097152);
    cvt_bf16<<<dim3(2048), blk, 0, stream>>>(wq, wqb, 2097152);
    // Q projection with fused RoPE
    gemm_bb<2><<<dim3(32, 32), blk, 0, stream>>>(xb, wqb, qws, nullptr, fc, fs,
                                                 4096, 4096, 4096);
    // wq dead -> stage wk/wv into d_out tail, outputs into wqb's region
    cvt_bf16<<<dim3(1024), blk, 0, stream>>>(wk, wkvb,                      524288);
    cvt_bf16<<<dim3(1024), blk, 0, stream>>>(wv, wkvb + (size_t)8 * 524288, 524288);
    // merged K+V projection: K roped row-major, V transposed; grid 512 blocks
    gemm_bb<3><<<dim3(16, 32), blk, 0, stream>>>(xb, wkvb, kws, vtws, fc, fs,
                                                 4096, 2048, 4096);
    flash_attn<<<dim3(16, 32, 2), blk, 0, stream>>>(qws, kws, vtws, qws);
    if (ws_size >= (size_t)(64u << 20)) {
        u16* wob = qws + (size_t)32 * 524288;
        cvt_bf16<<<dim3(2048), blk, 0, stream>>>(wo, wob, 2097152);
        gemm_bb<1><<<dim3(32, 32), blk, 0, stream>>>(qws, wob, out, nullptr,
                                                     nullptr, nullptr,
                                                     4096, 4096, 4096);
    } else {
        gemm_bt<true, true><<<dim3(32, 32), blk, 0, stream>>>(qws, wo, out,
                                                              4096, 4096, 4096);
    }
}